// Round 5
// baseline (2951.360 us; speedup 1.0000x reference)
//
#include <hip/hip_runtime.h>

// ---------------------------------------------------------------------------
// Mamba block. Inputs float32 (confirmed R4: bf16 reads of them produced NaN,
// fp32 branch produced finite output). Output float32 (reference returns
// fp32; not a bf16-converted problem since inputs are raw fp32; R4's bf16
// writes produced the observed element-interleaved absmax=6.98 signature).
// Internal: bf16 MFMA operands, fp32 accumulation and scan state.
// ---------------------------------------------------------------------------
#define BATCH   2
#define SEQ     2048
#define DMODEL  1024
#define DINNER  2048
#define DSTATE  16
#define DTRANK  64
#define MROWS   (BATCH * SEQ)   // 4096

typedef float floatx4 __attribute__((ext_vector_type(4)));
typedef __bf16 bf16x8 __attribute__((ext_vector_type(8)));

// ---------------------------------------------------------------------------
// K1: LayerNorm.  One block per row of 1024.  fp32 in, bf16 out (GEMM A-op).
// ---------------------------------------------------------------------------
__global__ __launch_bounds__(256) void ln_kernel(const float* __restrict__ x,
                                                 const float* __restrict__ w,
                                                 const float* __restrict__ b,
                                                 __bf16* __restrict__ xn) {
    int row = blockIdx.x;
    const float* xr = x + (size_t)row * DMODEL;
    float v[4], s = 0.f, ss = 0.f;
#pragma unroll
    for (int i = 0; i < 4; ++i) {
        v[i] = xr[threadIdx.x + i * 256];
        s += v[i]; ss += v[i] * v[i];
    }
#pragma unroll
    for (int o = 32; o > 0; o >>= 1) { s += __shfl_xor(s, o); ss += __shfl_xor(ss, o); }
    __shared__ float ps[4], pss[4];
    int wv = threadIdx.x >> 6;
    if ((threadIdx.x & 63) == 0) { ps[wv] = s; pss[wv] = ss; }
    __syncthreads();
    s  = ps[0] + ps[1] + ps[2] + ps[3];
    ss = pss[0] + pss[1] + pss[2] + pss[3];
    float mu  = s * (1.f / DMODEL);
    float var = ss * (1.f / DMODEL) - mu * mu;
    float rs  = rsqrtf(var + 1e-5f);
#pragma unroll
    for (int i = 0; i < 4; ++i) {
        int c = threadIdx.x + i * 256;
        xn[(size_t)row * DMODEL + c] = (__bf16)((v[i] - mu) * rs * w[c] + b[c]);
    }
}

// ---------------------------------------------------------------------------
// MFMA bf16 GEMM:  C[M,N] = A[M,K] * B[N,K]^T.  A: ws bf16.  B: fp32 weight,
// converted to bf16 during LDS staging.  128x128 tile, BK=32, 4 waves.
// EPI=1: split -> out0 bf16 (n<split) / out1 bf16 (n>=split)
// EPI=2: residual -> outf fp32 = acc + add[idx]
// Layouts (HW-verified): A/B frag [idx=lane&15][k=(lane>>4)*8+j];
// C/D col=lane&15, row=(lane>>4)*4+reg.
// ---------------------------------------------------------------------------
#define BM 128
#define BN 128
#define BK 32
#define LDK 48   // padded LDS K-stride (96 B rows; 16 B aligned)

template <int EPI>
__global__ __launch_bounds__(256) void gemm_bt(const __bf16* __restrict__ A,
                                               const float* __restrict__ B,
                                               int M, int N, int K,
                                               __bf16* __restrict__ out0,
                                               __bf16* __restrict__ out1,
                                               float* __restrict__ outf,
                                               const float* __restrict__ add,
                                               int split) {
    __shared__ __align__(16) __bf16 sA[BM][LDK];
    __shared__ __align__(16) __bf16 sB[BN][LDK];
    int tid  = threadIdx.x;
    int wave = tid >> 6, lane = tid & 63;
    int m0 = blockIdx.y * BM, n0 = blockIdx.x * BN;
    int wm = (wave & 1) * 64, wn = (wave >> 1) * 64;
    int lr = lane & 15;
    int lq = lane >> 4;

    floatx4 acc[4][4] = {};

    for (int k0 = 0; k0 < K; k0 += BK) {
#pragma unroll
        for (int c = tid; c < 512; c += 256) {
            int row = c >> 2, col = (c & 3) * 8;
            *(bf16x8*)&sA[row][col] = *(const bf16x8*)&A[(size_t)(m0 + row) * K + k0 + col];
        }
#pragma unroll
        for (int c = tid; c < 512; c += 256) {
            int row = c >> 2, col = (c & 3) * 8;
            const float* src = B + (size_t)(n0 + row) * K + k0 + col;
            floatx4 lo = *(const floatx4*)src;
            floatx4 hi = *(const floatx4*)(src + 4);
            bf16x8 v;
#pragma unroll
            for (int t = 0; t < 4; ++t) { v[t] = (__bf16)lo[t]; v[4 + t] = (__bf16)hi[t]; }
            *(bf16x8*)&sB[row][col] = v;
        }
        __syncthreads();

        bf16x8 af[4], bfr[4];
#pragma unroll
        for (int i = 0; i < 4; ++i) af[i]  = *(const bf16x8*)&sA[wm + i * 16 + lr][lq * 8];
#pragma unroll
        for (int j = 0; j < 4; ++j) bfr[j] = *(const bf16x8*)&sB[wn + j * 16 + lr][lq * 8];
#pragma unroll
        for (int i = 0; i < 4; ++i)
#pragma unroll
            for (int j = 0; j < 4; ++j)
                acc[i][j] = __builtin_amdgcn_mfma_f32_16x16x32_bf16(af[i], bfr[j], acc[i][j], 0, 0, 0);
        __syncthreads();
    }

#pragma unroll
    for (int i = 0; i < 4; ++i)
#pragma unroll
        for (int j = 0; j < 4; ++j) {
            int gn = n0 + wn + j * 16 + lr;
#pragma unroll
            for (int r = 0; r < 4; ++r) {
                int gm = m0 + wm + i * 16 + lq * 4 + r;
                float v = acc[i][j][r];
                if (EPI == 1) {
                    if (gn < split) out0[(size_t)gm * split + gn] = (__bf16)v;
                    else            out1[(size_t)gm * split + (gn - split)] = (__bf16)v;
                } else {
                    size_t idx = (size_t)gm * N + gn;
                    outf[idx] = v + add[idx];
                }
            }
        }
}

// ---------------------------------------------------------------------------
// K3: depthwise causal conv (width 4) + bias + SiLU.
// ---------------------------------------------------------------------------
__global__ __launch_bounds__(256) void conv_kernel(const __bf16* __restrict__ xin,
                                                   const float* __restrict__ cw,
                                                   const float* __restrict__ cb,
                                                   __bf16* __restrict__ u) {
    int idx = blockIdx.x * 256 + threadIdx.x;        // over MROWS*DINNER
    int d  = idx & (DINNER - 1);
    int bl = idx >> 11;                              // b*SEQ + l
    int l  = bl & (SEQ - 1);
    float acc = cb[d];
#pragma unroll
    for (int j = 0; j < 4; ++j) {
        int ll = l - 3 + j;
        if (ll >= 0) acc += (float)xin[(size_t)(bl - 3 + j) * DINNER + d] * cw[d * 4 + j];
    }
    float sg = 1.f / (1.f + __expf(-acc));
    u[idx] = (__bf16)(acc * sg);
}

// ---------------------------------------------------------------------------
// K4: x_dbl[m, 0..95] = u[m,:] @ W_x^T   (fp32 out: feeds the scan's B/C)
// ---------------------------------------------------------------------------
__global__ __launch_bounds__(128) void wx_kernel(const __bf16* __restrict__ u,
                                                 const float* __restrict__ Wx,
                                                 float* __restrict__ xdbl) {
    int m = blockIdx.x;
    __shared__ float su[DINNER];
    for (int i = threadIdx.x; i < DINNER; i += 128) su[i] = (float)u[(size_t)m * DINNER + i];
    __syncthreads();
    int n = threadIdx.x;
    if (n < 96) {
        const float* wr = Wx + (size_t)n * DINNER;
        float acc = 0.f;
        for (int k = 0; k < DINNER; k += 4) {
            floatx4 wvv = *(const floatx4*)&wr[k];
#pragma unroll
            for (int t = 0; t < 4; ++t) acc += su[k + t] * wvv[t];
        }
        xdbl[(size_t)m * 96 + n] = acc;
    }
}

// ---------------------------------------------------------------------------
// K5: dt[m,n] = softplus(x_dbl[m,0:64] @ W_dt[n,:] + b_dt[n])
// ---------------------------------------------------------------------------
__global__ __launch_bounds__(256) void dt_kernel(const float* __restrict__ xdbl,
                                                 const float* __restrict__ Wdt,
                                                 const float* __restrict__ bdt,
                                                 __bf16* __restrict__ dt) {
    int m = blockIdx.y;
    int n = blockIdx.x * 256 + threadIdx.x;
    __shared__ float sr[DTRANK];
    if (threadIdx.x < DTRANK) sr[threadIdx.x] = xdbl[(size_t)m * 96 + threadIdx.x];
    __syncthreads();
    const float* wr = Wdt + (size_t)n * DTRANK;
    float acc = bdt[n];
#pragma unroll
    for (int k = 0; k < DTRANK; k += 4) {
        floatx4 wvv = *(const floatx4*)&wr[k];
#pragma unroll
        for (int t = 0; t < 4; ++t) acc += sr[k + t] * wvv[t];
    }
    float sp = (acc > 20.f) ? acc : log1pf(__expf(acc));
    dt[(size_t)m * DINNER + n] = (__bf16)sp;
}

// ---------------------------------------------------------------------------
// K6: selective scan, sequential over L.  64 blocks x 64 threads; one thread
// per (b,d) channel, 16 fp32 states in registers.  B/C staged in LDS per
// 64-step chunk.  zy read (z) then overwritten (y) in place by same thread.
// ---------------------------------------------------------------------------
#define SCAN_T 64
__global__ __launch_bounds__(64) void scan_kernel(const __bf16* __restrict__ dt,
                                                  const __bf16* __restrict__ u,
                                                  const float* __restrict__ xdbl,
                                                  const float* __restrict__ Alog,
                                                  const float* __restrict__ Dp,
                                                  __bf16* zy) {
    int b    = blockIdx.x >> 5;          // 32 blocks per batch
    int d    = ((blockIdx.x & 31) << 6) + threadIdx.x;
    int lane = threadIdx.x;

    float A[DSTATE], h[DSTATE];
#pragma unroll
    for (int s = 0; s < DSTATE; ++s) {
        A[s] = -__expf(Alog[d * DSTATE + s]);
        h[s] = 0.f;
    }
    float Dv = Dp[d];

    __shared__ float sBC[SCAN_T][32];
    for (int lc = 0; lc < SEQ; lc += SCAN_T) {
        for (int i = 0; i < SCAN_T * 32 / 64; ++i) {
            int idx = i * 64 + lane;
            int lt = idx >> 5, s = idx & 31;
            sBC[lt][s] = xdbl[(size_t)(b * SEQ + lc + lt) * 96 + 64 + s];
        }
        __syncthreads();
        for (int t = 0; t < SCAN_T; ++t) {
            size_t row = (size_t)(b * SEQ + lc + t);
            float dtv = (float)dt[row * DINNER + d];
            float uv  = (float)u[row * DINNER + d];
            float du  = dtv * uv;
            float yv  = 0.f;
#pragma unroll
            for (int s = 0; s < DSTATE; ++s) {
                float e = __expf(dtv * A[s]);
                h[s] = e * h[s] + du * sBC[t][s];
                yv  += h[s] * sBC[t][16 + s];
            }
            float zv = (float)zy[row * DINNER + d];
            float sz = zv / (1.f + __expf(-zv));
            zy[row * DINNER + d] = (__bf16)((yv + uv * Dv) * sz);
        }
        __syncthreads();
    }
}

// ---------------------------------------------------------------------------
extern "C" void kernel_launch(void* const* d_in, const int* in_sizes, int n_in,
                              void* d_out, int out_size, void* d_ws, size_t ws_size,
                              hipStream_t stream) {
    const float* x      = (const float*)d_in[0];
    const float* ln_w   = (const float*)d_in[1];
    const float* ln_b   = (const float*)d_in[2];
    const float* W_in   = (const float*)d_in[3];
    const float* conv_w = (const float*)d_in[4];
    const float* conv_b = (const float*)d_in[5];
    const float* W_x    = (const float*)d_in[6];
    const float* W_dt   = (const float*)d_in[7];
    const float* b_dt   = (const float*)d_in[8];
    const float* A_log  = (const float*)d_in[9];
    const float* Dp     = (const float*)d_in[10];
    const float* W_out  = (const float*)d_in[11];
    float* out = (float*)d_out;

    // Workspace layout, 56 MiB peak (audited in bytes):
    //   [ 0M, 8M)  xn bf16 (8M; dead after GEMM1) -> xdbl fp32 [0,1.5M)
    //   [ 8M,24M)  x_in bf16 (16M; dead after conv) -> dt bf16 (16M)
    //   [24M,40M)  z bf16 16M; scan overwrites with y in place
    //   [40M,56M)  u bf16 16M
    char* ws = (char*)d_ws;
    __bf16* xn_bf  = (__bf16*)(ws);
    float*  xdbl   = (float*) (ws);
    __bf16* xin_bf = (__bf16*)(ws + (8ull  << 20));
    __bf16* dt_bf  = (__bf16*)(ws + (8ull  << 20));
    __bf16* zy_bf  = (__bf16*)(ws + (24ull << 20));
    __bf16* u_bf   = (__bf16*)(ws + (40ull << 20));

    ln_kernel<<<MROWS, 256, 0, stream>>>(x, ln_w, ln_b, xn_bf);

    gemm_bt<1><<<dim3(2 * DINNER / BN, MROWS / BM), 256, 0, stream>>>(
        xn_bf, W_in, MROWS, 2 * DINNER, DMODEL, xin_bf, zy_bf, nullptr, nullptr, DINNER);

    conv_kernel<<<MROWS * DINNER / 256, 256, 0, stream>>>(xin_bf, conv_w, conv_b, u_bf);

    wx_kernel<<<MROWS, 128, 0, stream>>>(u_bf, W_x, xdbl);

    dt_kernel<<<dim3(DINNER / 256, MROWS), 256, 0, stream>>>(xdbl, W_dt, b_dt, dt_bf);

    scan_kernel<<<BATCH * DINNER / 64, 64, 0, stream>>>(dt_bf, u_bf, xdbl, A_log, Dp, zy_bf);

    gemm_bt<2><<<dim3(DMODEL / BN, MROWS / BM), 256, 0, stream>>>(
        zy_bf, W_out, MROWS, DMODEL, DINNER, nullptr, nullptr, out, x, 0);
}

// Round 6
// 1036.153 us; speedup vs baseline: 2.8484x; 2.8484x over previous
//
#include <hip/hip_runtime.h>

// ---------------------------------------------------------------------------
// Mamba block. fp32 in/out (confirmed R4/R5). Internal: bf16 MFMA operands,
// fp32 accumulation and scan state.
// R6: sequential scan (2020 us @ 0.75% occupancy, latency-bound) replaced by
// 3-pass chunked parallel scan (linear recurrence composition).
// ---------------------------------------------------------------------------
#define BATCH   2
#define SEQ     2048
#define DMODEL  1024
#define DINNER  2048
#define DSTATE  16
#define DTRANK  64
#define MROWS   (BATCH * SEQ)   // 4096
#define CLEN    64              // scan chunk length
#define CHUNKS  (SEQ / CLEN)    // 32

typedef float floatx4 __attribute__((ext_vector_type(4)));
typedef __bf16 bf16x8 __attribute__((ext_vector_type(8)));

// ---------------------------------------------------------------------------
// K1: LayerNorm.  One block per row of 1024.  fp32 in, bf16 out (GEMM A-op).
// ---------------------------------------------------------------------------
__global__ __launch_bounds__(256) void ln_kernel(const float* __restrict__ x,
                                                 const float* __restrict__ w,
                                                 const float* __restrict__ b,
                                                 __bf16* __restrict__ xn) {
    int row = blockIdx.x;
    const float* xr = x + (size_t)row * DMODEL;
    float v[4], s = 0.f, ss = 0.f;
#pragma unroll
    for (int i = 0; i < 4; ++i) {
        v[i] = xr[threadIdx.x + i * 256];
        s += v[i]; ss += v[i] * v[i];
    }
#pragma unroll
    for (int o = 32; o > 0; o >>= 1) { s += __shfl_xor(s, o); ss += __shfl_xor(ss, o); }
    __shared__ float ps[4], pss[4];
    int wv = threadIdx.x >> 6;
    if ((threadIdx.x & 63) == 0) { ps[wv] = s; pss[wv] = ss; }
    __syncthreads();
    s  = ps[0] + ps[1] + ps[2] + ps[3];
    ss = pss[0] + pss[1] + pss[2] + pss[3];
    float mu  = s * (1.f / DMODEL);
    float var = ss * (1.f / DMODEL) - mu * mu;
    float rs  = rsqrtf(var + 1e-5f);
#pragma unroll
    for (int i = 0; i < 4; ++i) {
        int c = threadIdx.x + i * 256;
        xn[(size_t)row * DMODEL + c] = (__bf16)((v[i] - mu) * rs * w[c] + b[c]);
    }
}

// ---------------------------------------------------------------------------
// MFMA bf16 GEMM:  C[M,N] = A[M,K] * B[N,K]^T.  A: ws bf16.  B: fp32 weight,
// converted to bf16 during LDS staging.  128x128 tile, BK=32, 4 waves.
// EPI=1: split -> out0 bf16 (n<split) / out1 bf16 (n>=split)
// EPI=2: residual -> outf fp32 = acc + add[idx]
// ---------------------------------------------------------------------------
#define BM 128
#define BN 128
#define BK 32
#define LDK 48   // padded LDS K-stride

template <int EPI>
__global__ __launch_bounds__(256) void gemm_bt(const __bf16* __restrict__ A,
                                               const float* __restrict__ B,
                                               int M, int N, int K,
                                               __bf16* __restrict__ out0,
                                               __bf16* __restrict__ out1,
                                               float* __restrict__ outf,
                                               const float* __restrict__ add,
                                               int split) {
    __shared__ __align__(16) __bf16 sA[BM][LDK];
    __shared__ __align__(16) __bf16 sB[BN][LDK];
    int tid  = threadIdx.x;
    int wave = tid >> 6, lane = tid & 63;
    int m0 = blockIdx.y * BM, n0 = blockIdx.x * BN;
    int wm = (wave & 1) * 64, wn = (wave >> 1) * 64;
    int lr = lane & 15;
    int lq = lane >> 4;

    floatx4 acc[4][4] = {};

    for (int k0 = 0; k0 < K; k0 += BK) {
#pragma unroll
        for (int c = tid; c < 512; c += 256) {
            int row = c >> 2, col = (c & 3) * 8;
            *(bf16x8*)&sA[row][col] = *(const bf16x8*)&A[(size_t)(m0 + row) * K + k0 + col];
        }
#pragma unroll
        for (int c = tid; c < 512; c += 256) {
            int row = c >> 2, col = (c & 3) * 8;
            const float* src = B + (size_t)(n0 + row) * K + k0 + col;
            floatx4 lo = *(const floatx4*)src;
            floatx4 hi = *(const floatx4*)(src + 4);
            bf16x8 v;
#pragma unroll
            for (int t = 0; t < 4; ++t) { v[t] = (__bf16)lo[t]; v[4 + t] = (__bf16)hi[t]; }
            *(bf16x8*)&sB[row][col] = v;
        }
        __syncthreads();

        bf16x8 af[4], bfr[4];
#pragma unroll
        for (int i = 0; i < 4; ++i) af[i]  = *(const bf16x8*)&sA[wm + i * 16 + lr][lq * 8];
#pragma unroll
        for (int j = 0; j < 4; ++j) bfr[j] = *(const bf16x8*)&sB[wn + j * 16 + lr][lq * 8];
#pragma unroll
        for (int i = 0; i < 4; ++i)
#pragma unroll
            for (int j = 0; j < 4; ++j)
                acc[i][j] = __builtin_amdgcn_mfma_f32_16x16x32_bf16(af[i], bfr[j], acc[i][j], 0, 0, 0);
        __syncthreads();
    }

#pragma unroll
    for (int i = 0; i < 4; ++i)
#pragma unroll
        for (int j = 0; j < 4; ++j) {
            int gn = n0 + wn + j * 16 + lr;
#pragma unroll
            for (int r = 0; r < 4; ++r) {
                int gm = m0 + wm + i * 16 + lq * 4 + r;
                float v = acc[i][j][r];
                if (EPI == 1) {
                    if (gn < split) out0[(size_t)gm * split + gn] = (__bf16)v;
                    else            out1[(size_t)gm * split + (gn - split)] = (__bf16)v;
                } else {
                    size_t idx = (size_t)gm * N + gn;
                    outf[idx] = v + add[idx];
                }
            }
        }
}

// ---------------------------------------------------------------------------
// K3: depthwise causal conv (width 4) + bias + SiLU.
// ---------------------------------------------------------------------------
__global__ __launch_bounds__(256) void conv_kernel(const __bf16* __restrict__ xin,
                                                   const float* __restrict__ cw,
                                                   const float* __restrict__ cb,
                                                   __bf16* __restrict__ u) {
    int idx = blockIdx.x * 256 + threadIdx.x;        // over MROWS*DINNER
    int d  = idx & (DINNER - 1);
    int bl = idx >> 11;                              // b*SEQ + l
    int l  = bl & (SEQ - 1);
    float acc = cb[d];
#pragma unroll
    for (int j = 0; j < 4; ++j) {
        int ll = l - 3 + j;
        if (ll >= 0) acc += (float)xin[(size_t)(bl - 3 + j) * DINNER + d] * cw[d * 4 + j];
    }
    float sg = 1.f / (1.f + __expf(-acc));
    u[idx] = (__bf16)(acc * sg);
}

// ---------------------------------------------------------------------------
// K4: x_dbl[m, 0..95] = u[m,:] @ W_x^T   (fp32 out: feeds the scan's B/C)
// ---------------------------------------------------------------------------
__global__ __launch_bounds__(128) void wx_kernel(const __bf16* __restrict__ u,
                                                 const float* __restrict__ Wx,
                                                 float* __restrict__ xdbl) {
    int m = blockIdx.x;
    __shared__ float su[DINNER];
    for (int i = threadIdx.x; i < DINNER; i += 128) su[i] = (float)u[(size_t)m * DINNER + i];
    __syncthreads();
    int n = threadIdx.x;
    if (n < 96) {
        const float* wr = Wx + (size_t)n * DINNER;
        float acc = 0.f;
        for (int k = 0; k < DINNER; k += 4) {
            floatx4 wvv = *(const floatx4*)&wr[k];
#pragma unroll
            for (int t = 0; t < 4; ++t) acc += su[k + t] * wvv[t];
        }
        xdbl[(size_t)m * 96 + n] = acc;
    }
}

// ---------------------------------------------------------------------------
// K5: dt[m,n] = softplus(x_dbl[m,0:64] @ W_dt[n,:] + b_dt[n])
// ---------------------------------------------------------------------------
__global__ __launch_bounds__(256) void dt_kernel(const float* __restrict__ xdbl,
                                                 const float* __restrict__ Wdt,
                                                 const float* __restrict__ bdt,
                                                 __bf16* __restrict__ dt) {
    int m = blockIdx.y;
    int n = blockIdx.x * 256 + threadIdx.x;
    __shared__ float sr[DTRANK];
    if (threadIdx.x < DTRANK) sr[threadIdx.x] = xdbl[(size_t)m * 96 + threadIdx.x];
    __syncthreads();
    const float* wr = Wdt + (size_t)n * DTRANK;
    float acc = bdt[n];
#pragma unroll
    for (int k = 0; k < DTRANK; k += 4) {
        floatx4 wvv = *(const floatx4*)&wr[k];
#pragma unroll
        for (int t = 0; t < 4; ++t) acc += sr[k + t] * wvv[t];
    }
    float sp = (acc > 20.f) ? acc : log1pf(__expf(acc));
    dt[(size_t)m * DINNER + n] = (__bf16)sp;
}

// ---------------------------------------------------------------------------
// K6 (3-pass chunked scan).  h_t = exp(dt_t*A)*h_{t-1} + dt_t*u_t*B_t.
// Chunk composition: h_end = exp(A*Sum dt)*h_start + H_loc.
// grid pass1/3: (chunk c, d-block, batch); 64 threads = 64 channels.
// ---------------------------------------------------------------------------
__global__ __launch_bounds__(64) void scan_pass1(const __bf16* __restrict__ dt,
                                                 const __bf16* __restrict__ u,
                                                 const float* __restrict__ xdbl,
                                                 const float* __restrict__ Alog,
                                                 float* __restrict__ Sdt,
                                                 __bf16* __restrict__ Hfix) {
    int c = blockIdx.x, dblk = blockIdx.y, b = blockIdx.z;
    int lane = threadIdx.x;
    int d0 = dblk * 64, d = d0 + lane;
    int row0 = b * SEQ + c * CLEN;

    __shared__ __align__(16) __bf16 sdt[CLEN][64];
    __shared__ __align__(16) __bf16 su [CLEN][64];
    __shared__ __align__(16) float  sB [CLEN][DSTATE];

#pragma unroll
    for (int i = 0; i < 32; ++i) {           // 64x64 bf16 as 2048 u32
        int idx = i * 64 + lane, t = idx >> 5, p = idx & 31;
        ((unsigned*)&sdt[t][0])[p] = *(const unsigned*)(dt + (size_t)(row0 + t) * DINNER + d0 + p * 2);
        ((unsigned*)&su [t][0])[p] = *(const unsigned*)(u  + (size_t)(row0 + t) * DINNER + d0 + p * 2);
    }
#pragma unroll
    for (int i = 0; i < 4; ++i) {            // 64x16 fp32 as 256 float4
        int idx = i * 64 + lane, t = idx >> 2, q = idx & 3;
        *(floatx4*)&sB[t][q * 4] = *(const floatx4*)&xdbl[(size_t)(row0 + t) * 96 + 64 + q * 4];
    }
    __syncthreads();

    float A[DSTATE], h[DSTATE];
#pragma unroll
    for (int s = 0; s < DSTATE; ++s) { A[s] = -__expf(Alog[d * DSTATE + s]); h[s] = 0.f; }

    float S = 0.f;
    for (int t = 0; t < CLEN; ++t) {
        float dtv = (float)sdt[t][lane];
        float du  = dtv * (float)su[t][lane];
        S += dtv;
#pragma unroll
        for (int s = 0; s < DSTATE; ++s)
            h[s] = __expf(dtv * A[s]) * h[s] + du * sB[t][s];
    }
    size_t ch = ((size_t)(b * DINNER + d) * CHUNKS + c);
    Sdt[ch] = S;
#pragma unroll
    for (int s = 0; s < DSTATE; ++s) Hfix[ch * DSTATE + s] = (__bf16)h[s];
}

// Pass 2: per (b,d,s) chain over 32 chunk summaries; Hfix rewritten in place
// from H_loc to h_init (state at chunk start).
__global__ __launch_bounds__(256) void scan_pass2(const float* __restrict__ Alog,
                                                  const float* __restrict__ Sdt,
                                                  __bf16* __restrict__ Hfix) {
    int g = blockIdx.x * 256 + threadIdx.x;       // over BATCH*DINNER*DSTATE
    int s = g & (DSTATE - 1);
    int bd = g >> 4;                              // b*DINNER + d
    int d = bd & (DINNER - 1);
    float A = -__expf(Alog[d * DSTATE + s]);
    size_t hbase = (size_t)bd * CHUNKS * DSTATE + s;
    size_t sbase = (size_t)bd * CHUNKS;
    float h = 0.f;
#pragma unroll 4
    for (int c = 0; c < CHUNKS; ++c) {
        float Hl = (float)Hfix[hbase + c * DSTATE];
        float P  = __expf(A * Sdt[sbase + c]);
        Hfix[hbase + c * DSTATE] = (__bf16)h;     // h_init for chunk c
        h = P * h + Hl;
    }
}

// Pass 3: recompute scan per chunk from h_init; fused epilogue
// y = (scan_y + u*D) * silu(z), written over z in place.
__global__ __launch_bounds__(64) void scan_pass3(const __bf16* __restrict__ dt,
                                                 const __bf16* __restrict__ u,
                                                 const float* __restrict__ xdbl,
                                                 const float* __restrict__ Alog,
                                                 const float* __restrict__ Dp,
                                                 const __bf16* __restrict__ Hfix,
                                                 __bf16* zy) {
    int c = blockIdx.x, dblk = blockIdx.y, b = blockIdx.z;
    int lane = threadIdx.x;
    int d0 = dblk * 64, d = d0 + lane;
    int row0 = b * SEQ + c * CLEN;

    __shared__ __align__(16) __bf16 sdt[CLEN][64];
    __shared__ __align__(16) __bf16 su [CLEN][64];
    __shared__ __align__(16) __bf16 sz [CLEN][64];
    __shared__ __align__(16) float  sBC[CLEN][2 * DSTATE];

#pragma unroll
    for (int i = 0; i < 32; ++i) {
        int idx = i * 64 + lane, t = idx >> 5, p = idx & 31;
        ((unsigned*)&sdt[t][0])[p] = *(const unsigned*)(dt + (size_t)(row0 + t) * DINNER + d0 + p * 2);
        ((unsigned*)&su [t][0])[p] = *(const unsigned*)(u  + (size_t)(row0 + t) * DINNER + d0 + p * 2);
        ((unsigned*)&sz [t][0])[p] = *(const unsigned*)((const __bf16*)zy + (size_t)(row0 + t) * DINNER + d0 + p * 2);
    }
#pragma unroll
    for (int i = 0; i < 8; ++i) {            // 64x32 fp32 as 512 float4
        int idx = i * 64 + lane, t = idx >> 3, q = idx & 7;
        *(floatx4*)&sBC[t][q * 4] = *(const floatx4*)&xdbl[(size_t)(row0 + t) * 96 + 64 + q * 4];
    }
    __syncthreads();

    float A[DSTATE], h[DSTATE];
    size_t ch = ((size_t)(b * DINNER + d) * CHUNKS + c);
#pragma unroll
    for (int s = 0; s < DSTATE; ++s) {
        A[s] = -__expf(Alog[d * DSTATE + s]);
        h[s] = (float)Hfix[ch * DSTATE + s];
    }
    float Dv = Dp[d];

    for (int t = 0; t < CLEN; ++t) {
        float dtv = (float)sdt[t][lane];
        float uv  = (float)su[t][lane];
        float du  = dtv * uv;
        float yv  = 0.f;
#pragma unroll
        for (int s = 0; s < DSTATE; ++s) {
            h[s] = __expf(dtv * A[s]) * h[s] + du * sBC[t][s];
            yv  += h[s] * sBC[t][DSTATE + s];
        }
        float zv = (float)sz[t][lane];
        float sg = zv / (1.f + __expf(-zv));
        zy[(size_t)(row0 + t) * DINNER + d] = (__bf16)((yv + uv * Dv) * sg);
    }
}

// ---------------------------------------------------------------------------
extern "C" void kernel_launch(void* const* d_in, const int* in_sizes, int n_in,
                              void* d_out, int out_size, void* d_ws, size_t ws_size,
                              hipStream_t stream) {
    const float* x      = (const float*)d_in[0];
    const float* ln_w   = (const float*)d_in[1];
    const float* ln_b   = (const float*)d_in[2];
    const float* W_in   = (const float*)d_in[3];
    const float* conv_w = (const float*)d_in[4];
    const float* conv_b = (const float*)d_in[5];
    const float* W_x    = (const float*)d_in[6];
    const float* W_dt   = (const float*)d_in[7];
    const float* b_dt   = (const float*)d_in[8];
    const float* A_log  = (const float*)d_in[9];
    const float* Dp     = (const float*)d_in[10];
    const float* W_out  = (const float*)d_in[11];
    float* out = (float*)d_out;

    // Workspace, 56 MiB peak:
    //   [ 0,  8M)  xn bf16 (dead after GEMM1) -> { xdbl fp32 [0,1.5M),
    //              Sdt fp32 [1.5M,2M), Hfix bf16 [2M,6M) }
    //   [ 8M,24M)  x_in bf16 (dead after conv) -> dt bf16
    //   [24M,40M)  z bf16; scan pass3 overwrites with y in place
    //   [40M,56M)  u bf16
    char* ws = (char*)d_ws;
    __bf16* xn_bf  = (__bf16*)(ws);
    float*  xdbl   = (float*) (ws);
    float*  Sdt    = (float*) (ws + 1536ull * 1024);
    __bf16* Hfix   = (__bf16*)(ws + (2ull  << 20));
    __bf16* xin_bf = (__bf16*)(ws + (8ull  << 20));
    __bf16* dt_bf  = (__bf16*)(ws + (8ull  << 20));
    __bf16* zy_bf  = (__bf16*)(ws + (24ull << 20));
    __bf16* u_bf   = (__bf16*)(ws + (40ull << 20));

    ln_kernel<<<MROWS, 256, 0, stream>>>(x, ln_w, ln_b, xn_bf);

    gemm_bt<1><<<dim3(2 * DINNER / BN, MROWS / BM), 256, 0, stream>>>(
        xn_bf, W_in, MROWS, 2 * DINNER, DMODEL, xin_bf, zy_bf, nullptr, nullptr, DINNER);

    conv_kernel<<<MROWS * DINNER / 256, 256, 0, stream>>>(xin_bf, conv_w, conv_b, u_bf);

    wx_kernel<<<MROWS, 128, 0, stream>>>(u_bf, W_x, xdbl);

    dt_kernel<<<dim3(DINNER / 256, MROWS), 256, 0, stream>>>(xdbl, W_dt, b_dt, dt_bf);

    dim3 sgrid(CHUNKS, DINNER / 64, BATCH);
    scan_pass1<<<sgrid, 64, 0, stream>>>(dt_bf, u_bf, xdbl, A_log, Sdt, Hfix);
    scan_pass2<<<BATCH * DINNER * DSTATE / 256, 256, 0, stream>>>(A_log, Sdt, Hfix);
    scan_pass3<<<sgrid, 64, 0, stream>>>(dt_bf, u_bf, xdbl, A_log, Dp, Hfix, zy_bf);

    gemm_bt<2><<<dim3(DMODEL / BN, MROWS / BM), 256, 0, stream>>>(
        zy_bf, W_out, MROWS, DMODEL, DINNER, nullptr, nullptr, out, x, 0);
}

// Round 7
// 547.063 us; speedup vs baseline: 5.3949x; 1.8940x over previous
//
#include <hip/hip_runtime.h>

// ---------------------------------------------------------------------------
// Mamba block. fp32 in/out. Internal: bf16 MFMA operands, fp32 accumulation
// and scan state.
// R7: wx_kernel (384 us, scalar-FMA, 3 GB L2 re-reads) and dt_kernel moved
// to MFMA tile kernels. Scan is the R6 3-pass chunked parallel scan.
// ---------------------------------------------------------------------------
#define BATCH   2
#define SEQ     2048
#define DMODEL  1024
#define DINNER  2048
#define DSTATE  16
#define DTRANK  64
#define MROWS   (BATCH * SEQ)   // 4096
#define CLEN    64              // scan chunk length
#define CHUNKS  (SEQ / CLEN)    // 32

typedef float floatx4 __attribute__((ext_vector_type(4)));
typedef __bf16 bf16x8 __attribute__((ext_vector_type(8)));

// ---------------------------------------------------------------------------
// K1: LayerNorm.  One block per row of 1024.  fp32 in, bf16 out (GEMM A-op).
// ---------------------------------------------------------------------------
__global__ __launch_bounds__(256) void ln_kernel(const float* __restrict__ x,
                                                 const float* __restrict__ w,
                                                 const float* __restrict__ b,
                                                 __bf16* __restrict__ xn) {
    int row = blockIdx.x;
    const float* xr = x + (size_t)row * DMODEL;
    float v[4], s = 0.f, ss = 0.f;
#pragma unroll
    for (int i = 0; i < 4; ++i) {
        v[i] = xr[threadIdx.x + i * 256];
        s += v[i]; ss += v[i] * v[i];
    }
#pragma unroll
    for (int o = 32; o > 0; o >>= 1) { s += __shfl_xor(s, o); ss += __shfl_xor(ss, o); }
    __shared__ float ps[4], pss[4];
    int wv = threadIdx.x >> 6;
    if ((threadIdx.x & 63) == 0) { ps[wv] = s; pss[wv] = ss; }
    __syncthreads();
    s  = ps[0] + ps[1] + ps[2] + ps[3];
    ss = pss[0] + pss[1] + pss[2] + pss[3];
    float mu  = s * (1.f / DMODEL);
    float var = ss * (1.f / DMODEL) - mu * mu;
    float rs  = rsqrtf(var + 1e-5f);
#pragma unroll
    for (int i = 0; i < 4; ++i) {
        int c = threadIdx.x + i * 256;
        xn[(size_t)row * DMODEL + c] = (__bf16)((v[i] - mu) * rs * w[c] + b[c]);
    }
}

// ---------------------------------------------------------------------------
// MFMA bf16 GEMM:  C[M,N] = A[M,K] * B[N,K]^T.  A: ws bf16.  B: fp32 weight,
// converted to bf16 during LDS staging.  128x128 tile, BK=32, 4 waves.
// EPI=1: split -> out0 bf16 (n<split) / out1 bf16 (n>=split)
// EPI=2: residual -> outf fp32 = acc + add[idx]
// ---------------------------------------------------------------------------
#define BM 128
#define BN 128
#define BK 32
#define LDK 48   // padded LDS K-stride

template <int EPI>
__global__ __launch_bounds__(256) void gemm_bt(const __bf16* __restrict__ A,
                                               const float* __restrict__ B,
                                               int M, int N, int K,
                                               __bf16* __restrict__ out0,
                                               __bf16* __restrict__ out1,
                                               float* __restrict__ outf,
                                               const float* __restrict__ add,
                                               int split) {
    __shared__ __align__(16) __bf16 sA[BM][LDK];
    __shared__ __align__(16) __bf16 sB[BN][LDK];
    int tid  = threadIdx.x;
    int wave = tid >> 6, lane = tid & 63;
    int m0 = blockIdx.y * BM, n0 = blockIdx.x * BN;
    int wm = (wave & 1) * 64, wn = (wave >> 1) * 64;
    int lr = lane & 15;
    int lq = lane >> 4;

    floatx4 acc[4][4] = {};

    for (int k0 = 0; k0 < K; k0 += BK) {
#pragma unroll
        for (int c = tid; c < 512; c += 256) {
            int row = c >> 2, col = (c & 3) * 8;
            *(bf16x8*)&sA[row][col] = *(const bf16x8*)&A[(size_t)(m0 + row) * K + k0 + col];
        }
#pragma unroll
        for (int c = tid; c < 512; c += 256) {
            int row = c >> 2, col = (c & 3) * 8;
            const float* src = B + (size_t)(n0 + row) * K + k0 + col;
            floatx4 lo = *(const floatx4*)src;
            floatx4 hi = *(const floatx4*)(src + 4);
            bf16x8 v;
#pragma unroll
            for (int t = 0; t < 4; ++t) { v[t] = (__bf16)lo[t]; v[4 + t] = (__bf16)hi[t]; }
            *(bf16x8*)&sB[row][col] = v;
        }
        __syncthreads();

        bf16x8 af[4], bfr[4];
#pragma unroll
        for (int i = 0; i < 4; ++i) af[i]  = *(const bf16x8*)&sA[wm + i * 16 + lr][lq * 8];
#pragma unroll
        for (int j = 0; j < 4; ++j) bfr[j] = *(const bf16x8*)&sB[wn + j * 16 + lr][lq * 8];
#pragma unroll
        for (int i = 0; i < 4; ++i)
#pragma unroll
            for (int j = 0; j < 4; ++j)
                acc[i][j] = __builtin_amdgcn_mfma_f32_16x16x32_bf16(af[i], bfr[j], acc[i][j], 0, 0, 0);
        __syncthreads();
    }

#pragma unroll
    for (int i = 0; i < 4; ++i)
#pragma unroll
        for (int j = 0; j < 4; ++j) {
            int gn = n0 + wn + j * 16 + lr;
#pragma unroll
            for (int r = 0; r < 4; ++r) {
                int gm = m0 + wm + i * 16 + lq * 4 + r;
                float v = acc[i][j][r];
                if (EPI == 1) {
                    if (gn < split) out0[(size_t)gm * split + gn] = (__bf16)v;
                    else            out1[(size_t)gm * split + (gn - split)] = (__bf16)v;
                } else {
                    size_t idx = (size_t)gm * N + gn;
                    outf[idx] = v + add[idx];
                }
            }
        }
}

// ---------------------------------------------------------------------------
// K3: depthwise causal conv (width 4) + bias + SiLU.
// ---------------------------------------------------------------------------
__global__ __launch_bounds__(256) void conv_kernel(const __bf16* __restrict__ xin,
                                                   const float* __restrict__ cw,
                                                   const float* __restrict__ cb,
                                                   __bf16* __restrict__ u) {
    int idx = blockIdx.x * 256 + threadIdx.x;        // over MROWS*DINNER
    int d  = idx & (DINNER - 1);
    int bl = idx >> 11;                              // b*SEQ + l
    int l  = bl & (SEQ - 1);
    float acc = cb[d];
#pragma unroll
    for (int j = 0; j < 4; ++j) {
        int ll = l - 3 + j;
        if (ll >= 0) acc += (float)xin[(size_t)(bl - 3 + j) * DINNER + d] * cw[d * 4 + j];
    }
    float sg = 1.f / (1.f + __expf(-acc));
    u[idx] = (__bf16)(acc * sg);
}

// ---------------------------------------------------------------------------
// K4 (MFMA): xdbl[4096,96] = u[4096,2048] @ Wx[96,2048]^T, fp32 out.
// BM=128 x BN=96; 4 waves 2x2, each 64x48 (acc[4][3]); full K per block;
// grid = 32 m-blocks.  Wx staged to LDS once per block (kills the 3 GB of
// per-block L2 re-reads that made the scalar version 384 us).
// ---------------------------------------------------------------------------
__global__ __launch_bounds__(256) void wx_mfma(const __bf16* __restrict__ A,
                                               const float* __restrict__ B,
                                               float* __restrict__ xdbl) {
    __shared__ __align__(16) __bf16 sA[BM][LDK];
    __shared__ __align__(16) __bf16 sB[96][LDK];
    int tid  = threadIdx.x;
    int wave = tid >> 6, lane = tid & 63;
    int m0 = blockIdx.x * BM;
    int wm = (wave & 1) * 64, wn = (wave >> 1) * 48;
    int lr = lane & 15;
    int lq = lane >> 4;

    floatx4 acc[4][3] = {};

    for (int k0 = 0; k0 < DINNER; k0 += BK) {
#pragma unroll
        for (int c = tid; c < 512; c += 256) {
            int row = c >> 2, col = (c & 3) * 8;
            *(bf16x8*)&sA[row][col] = *(const bf16x8*)&A[(size_t)(m0 + row) * DINNER + k0 + col];
        }
        for (int c = tid; c < 384; c += 256) {
            int row = c >> 2, col = (c & 3) * 8;
            const float* src = B + (size_t)row * DINNER + k0 + col;
            floatx4 lo = *(const floatx4*)src;
            floatx4 hi = *(const floatx4*)(src + 4);
            bf16x8 v;
#pragma unroll
            for (int t = 0; t < 4; ++t) { v[t] = (__bf16)lo[t]; v[4 + t] = (__bf16)hi[t]; }
            *(bf16x8*)&sB[row][col] = v;
        }
        __syncthreads();

        bf16x8 af[4], bfr[3];
#pragma unroll
        for (int i = 0; i < 4; ++i) af[i]  = *(const bf16x8*)&sA[wm + i * 16 + lr][lq * 8];
#pragma unroll
        for (int j = 0; j < 3; ++j) bfr[j] = *(const bf16x8*)&sB[wn + j * 16 + lr][lq * 8];
#pragma unroll
        for (int i = 0; i < 4; ++i)
#pragma unroll
            for (int j = 0; j < 3; ++j)
                acc[i][j] = __builtin_amdgcn_mfma_f32_16x16x32_bf16(af[i], bfr[j], acc[i][j], 0, 0, 0);
        __syncthreads();
    }

#pragma unroll
    for (int i = 0; i < 4; ++i)
#pragma unroll
        for (int j = 0; j < 3; ++j) {
            int gn = wn + j * 16 + lr;
#pragma unroll
            for (int r = 0; r < 4; ++r) {
                int gm = m0 + wm + i * 16 + lq * 4 + r;
                xdbl[(size_t)gm * 96 + gn] = acc[i][j][r];
            }
        }
}

// ---------------------------------------------------------------------------
// K5 (MFMA): dt[4096,2048] = softplus(xdbl[:,0:64] @ Wdt[2048,64]^T + b_dt),
// bf16 out.  128x128 tile, K=64 (2 BK iters), grid 16x32.
// ---------------------------------------------------------------------------
__global__ __launch_bounds__(256) void dt_mfma(const float* __restrict__ Af,
                                               const float* __restrict__ B,
                                               const float* __restrict__ bdt,
                                               __bf16* __restrict__ dt) {
    __shared__ __align__(16) __bf16 sA[BM][LDK];
    __shared__ __align__(16) __bf16 sB[BN][LDK];
    int tid  = threadIdx.x;
    int wave = tid >> 6, lane = tid & 63;
    int m0 = blockIdx.y * BM, n0 = blockIdx.x * BN;
    int wm = (wave & 1) * 64, wn = (wave >> 1) * 64;
    int lr = lane & 15;
    int lq = lane >> 4;

    floatx4 acc[4][4] = {};

    for (int k0 = 0; k0 < DTRANK; k0 += BK) {
#pragma unroll
        for (int c = tid; c < 512; c += 256) {
            int row = c >> 2, col = (c & 3) * 8;
            const float* src = Af + (size_t)(m0 + row) * 96 + k0 + col;
            floatx4 lo = *(const floatx4*)src;
            floatx4 hi = *(const floatx4*)(src + 4);
            bf16x8 v;
#pragma unroll
            for (int t = 0; t < 4; ++t) { v[t] = (__bf16)lo[t]; v[4 + t] = (__bf16)hi[t]; }
            *(bf16x8*)&sA[row][col] = v;
        }
#pragma unroll
        for (int c = tid; c < 512; c += 256) {
            int row = c >> 2, col = (c & 3) * 8;
            const float* src = B + (size_t)(n0 + row) * DTRANK + k0 + col;
            floatx4 lo = *(const floatx4*)src;
            floatx4 hi = *(const floatx4*)(src + 4);
            bf16x8 v;
#pragma unroll
            for (int t = 0; t < 4; ++t) { v[t] = (__bf16)lo[t]; v[4 + t] = (__bf16)hi[t]; }
            *(bf16x8*)&sB[row][col] = v;
        }
        __syncthreads();

        bf16x8 af[4], bfr[4];
#pragma unroll
        for (int i = 0; i < 4; ++i) af[i]  = *(const bf16x8*)&sA[wm + i * 16 + lr][lq * 8];
#pragma unroll
        for (int j = 0; j < 4; ++j) bfr[j] = *(const bf16x8*)&sB[wn + j * 16 + lr][lq * 8];
#pragma unroll
        for (int i = 0; i < 4; ++i)
#pragma unroll
            for (int j = 0; j < 4; ++j)
                acc[i][j] = __builtin_amdgcn_mfma_f32_16x16x32_bf16(af[i], bfr[j], acc[i][j], 0, 0, 0);
        __syncthreads();
    }

#pragma unroll
    for (int i = 0; i < 4; ++i)
#pragma unroll
        for (int j = 0; j < 4; ++j) {
            int gn = n0 + wn + j * 16 + lr;
            float bv = bdt[gn];
#pragma unroll
            for (int r = 0; r < 4; ++r) {
                int gm = m0 + wm + i * 16 + lq * 4 + r;
                float a = acc[i][j][r] + bv;
                float sp = (a > 20.f) ? a : log1pf(__expf(a));
                dt[(size_t)gm * DINNER + gn] = (__bf16)sp;
            }
        }
}

// ---------------------------------------------------------------------------
// K6 (3-pass chunked scan).  h_t = exp(dt_t*A)*h_{t-1} + dt_t*u_t*B_t.
// ---------------------------------------------------------------------------
__global__ __launch_bounds__(64) void scan_pass1(const __bf16* __restrict__ dt,
                                                 const __bf16* __restrict__ u,
                                                 const float* __restrict__ xdbl,
                                                 const float* __restrict__ Alog,
                                                 float* __restrict__ Sdt,
                                                 __bf16* __restrict__ Hfix) {
    int c = blockIdx.x, dblk = blockIdx.y, b = blockIdx.z;
    int lane = threadIdx.x;
    int d0 = dblk * 64, d = d0 + lane;
    int row0 = b * SEQ + c * CLEN;

    __shared__ __align__(16) __bf16 sdt[CLEN][64];
    __shared__ __align__(16) __bf16 su [CLEN][64];
    __shared__ __align__(16) float  sB [CLEN][DSTATE];

#pragma unroll
    for (int i = 0; i < 32; ++i) {           // 64x64 bf16 as 2048 u32
        int idx = i * 64 + lane, t = idx >> 5, p = idx & 31;
        ((unsigned*)&sdt[t][0])[p] = *(const unsigned*)(dt + (size_t)(row0 + t) * DINNER + d0 + p * 2);
        ((unsigned*)&su [t][0])[p] = *(const unsigned*)(u  + (size_t)(row0 + t) * DINNER + d0 + p * 2);
    }
#pragma unroll
    for (int i = 0; i < 4; ++i) {            // 64x16 fp32 as 256 float4
        int idx = i * 64 + lane, t = idx >> 2, q = idx & 3;
        *(floatx4*)&sB[t][q * 4] = *(const floatx4*)&xdbl[(size_t)(row0 + t) * 96 + 64 + q * 4];
    }
    __syncthreads();

    float A[DSTATE], h[DSTATE];
#pragma unroll
    for (int s = 0; s < DSTATE; ++s) { A[s] = -__expf(Alog[d * DSTATE + s]); h[s] = 0.f; }

    float S = 0.f;
    for (int t = 0; t < CLEN; ++t) {
        float dtv = (float)sdt[t][lane];
        float du  = dtv * (float)su[t][lane];
        S += dtv;
#pragma unroll
        for (int s = 0; s < DSTATE; ++s)
            h[s] = __expf(dtv * A[s]) * h[s] + du * sB[t][s];
    }
    size_t ch = ((size_t)(b * DINNER + d) * CHUNKS + c);
    Sdt[ch] = S;
#pragma unroll
    for (int s = 0; s < DSTATE; ++s) Hfix[ch * DSTATE + s] = (__bf16)h[s];
}

// Pass 2: per (b,d,s) chain over 32 chunk summaries; Hfix rewritten in place
// from H_loc to h_init (state at chunk start).
__global__ __launch_bounds__(256) void scan_pass2(const float* __restrict__ Alog,
                                                  const float* __restrict__ Sdt,
                                                  __bf16* __restrict__ Hfix) {
    int g = blockIdx.x * 256 + threadIdx.x;       // over BATCH*DINNER*DSTATE
    int s = g & (DSTATE - 1);
    int bd = g >> 4;                              // b*DINNER + d
    int d = bd & (DINNER - 1);
    float A = -__expf(Alog[d * DSTATE + s]);
    size_t hbase = (size_t)bd * CHUNKS * DSTATE + s;
    size_t sbase = (size_t)bd * CHUNKS;
    float h = 0.f;
#pragma unroll 4
    for (int c = 0; c < CHUNKS; ++c) {
        float Hl = (float)Hfix[hbase + c * DSTATE];
        float P  = __expf(A * Sdt[sbase + c]);
        Hfix[hbase + c * DSTATE] = (__bf16)h;     // h_init for chunk c
        h = P * h + Hl;
    }
}

// Pass 3: recompute scan per chunk from h_init; fused epilogue
// y = (scan_y + u*D) * silu(z), written over z in place.
__global__ __launch_bounds__(64) void scan_pass3(const __bf16* __restrict__ dt,
                                                 const __bf16* __restrict__ u,
                                                 const float* __restrict__ xdbl,
                                                 const float* __restrict__ Alog,
                                                 const float* __restrict__ Dp,
                                                 const __bf16* __restrict__ Hfix,
                                                 __bf16* zy) {
    int c = blockIdx.x, dblk = blockIdx.y, b = blockIdx.z;
    int lane = threadIdx.x;
    int d0 = dblk * 64, d = d0 + lane;
    int row0 = b * SEQ + c * CLEN;

    __shared__ __align__(16) __bf16 sdt[CLEN][64];
    __shared__ __align__(16) __bf16 su [CLEN][64];
    __shared__ __align__(16) __bf16 sz [CLEN][64];
    __shared__ __align__(16) float  sBC[CLEN][2 * DSTATE];

#pragma unroll
    for (int i = 0; i < 32; ++i) {
        int idx = i * 64 + lane, t = idx >> 5, p = idx & 31;
        ((unsigned*)&sdt[t][0])[p] = *(const unsigned*)(dt + (size_t)(row0 + t) * DINNER + d0 + p * 2);
        ((unsigned*)&su [t][0])[p] = *(const unsigned*)(u  + (size_t)(row0 + t) * DINNER + d0 + p * 2);
        ((unsigned*)&sz [t][0])[p] = *(const unsigned*)((const __bf16*)zy + (size_t)(row0 + t) * DINNER + d0 + p * 2);
    }
#pragma unroll
    for (int i = 0; i < 8; ++i) {            // 64x32 fp32 as 512 float4
        int idx = i * 64 + lane, t = idx >> 3, q = idx & 7;
        *(floatx4*)&sBC[t][q * 4] = *(const floatx4*)&xdbl[(size_t)(row0 + t) * 96 + 64 + q * 4];
    }
    __syncthreads();

    float A[DSTATE], h[DSTATE];
    size_t ch = ((size_t)(b * DINNER + d) * CHUNKS + c);
#pragma unroll
    for (int s = 0; s < DSTATE; ++s) {
        A[s] = -__expf(Alog[d * DSTATE + s]);
        h[s] = (float)Hfix[ch * DSTATE + s];
    }
    float Dv = Dp[d];

    for (int t = 0; t < CLEN; ++t) {
        float dtv = (float)sdt[t][lane];
        float uv  = (float)su[t][lane];
        float du  = dtv * uv;
        float yv  = 0.f;
#pragma unroll
        for (int s = 0; s < DSTATE; ++s) {
            h[s] = __expf(dtv * A[s]) * h[s] + du * sBC[t][s];
            yv  += h[s] * sBC[t][DSTATE + s];
        }
        float zv = (float)sz[t][lane];
        float sg = zv / (1.f + __expf(-zv));
        zy[(size_t)(row0 + t) * DINNER + d] = (__bf16)((yv + uv * Dv) * sg);
    }
}

// ---------------------------------------------------------------------------
extern "C" void kernel_launch(void* const* d_in, const int* in_sizes, int n_in,
                              void* d_out, int out_size, void* d_ws, size_t ws_size,
                              hipStream_t stream) {
    const float* x      = (const float*)d_in[0];
    const float* ln_w   = (const float*)d_in[1];
    const float* ln_b   = (const float*)d_in[2];
    const float* W_in   = (const float*)d_in[3];
    const float* conv_w = (const float*)d_in[4];
    const float* conv_b = (const float*)d_in[5];
    const float* W_x    = (const float*)d_in[6];
    const float* W_dt   = (const float*)d_in[7];
    const float* b_dt   = (const float*)d_in[8];
    const float* A_log  = (const float*)d_in[9];
    const float* Dp     = (const float*)d_in[10];
    const float* W_out  = (const float*)d_in[11];
    float* out = (float*)d_out;

    // Workspace, 56 MiB peak:
    //   [ 0,  8M)  xn bf16 (dead after GEMM1) -> { xdbl fp32 [0,1.5M),
    //              Sdt fp32 [1.5M,2M), Hfix bf16 [2M,6M) }
    //   [ 8M,24M)  x_in bf16 (dead after conv) -> dt bf16
    //   [24M,40M)  z bf16; scan pass3 overwrites with y in place
    //   [40M,56M)  u bf16
    char* ws = (char*)d_ws;
    __bf16* xn_bf  = (__bf16*)(ws);
    float*  xdbl   = (float*) (ws);
    float*  Sdt    = (float*) (ws + 1536ull * 1024);
    __bf16* Hfix   = (__bf16*)(ws + (2ull  << 20));
    __bf16* xin_bf = (__bf16*)(ws + (8ull  << 20));
    __bf16* dt_bf  = (__bf16*)(ws + (8ull  << 20));
    __bf16* zy_bf  = (__bf16*)(ws + (24ull << 20));
    __bf16* u_bf   = (__bf16*)(ws + (40ull << 20));

    ln_kernel<<<MROWS, 256, 0, stream>>>(x, ln_w, ln_b, xn_bf);

    gemm_bt<1><<<dim3(2 * DINNER / BN, MROWS / BM), 256, 0, stream>>>(
        xn_bf, W_in, MROWS, 2 * DINNER, DMODEL, xin_bf, zy_bf, nullptr, nullptr, DINNER);

    conv_kernel<<<MROWS * DINNER / 256, 256, 0, stream>>>(xin_bf, conv_w, conv_b, u_bf);

    wx_mfma<<<MROWS / BM, 256, 0, stream>>>(u_bf, W_x, xdbl);

    dt_mfma<<<dim3(DINNER / BN, MROWS / BM), 256, 0, stream>>>(xdbl, W_dt, b_dt, dt_bf);

    dim3 sgrid(CHUNKS, DINNER / 64, BATCH);
    scan_pass1<<<sgrid, 64, 0, stream>>>(dt_bf, u_bf, xdbl, A_log, Sdt, Hfix);
    scan_pass2<<<BATCH * DINNER * DSTATE / 256, 256, 0, stream>>>(A_log, Sdt, Hfix);
    scan_pass3<<<sgrid, 64, 0, stream>>>(dt_bf, u_bf, xdbl, A_log, Dp, Hfix, zy_bf);

    gemm_bt<2><<<dim3(DMODEL / BN, MROWS / BM), 256, 0, stream>>>(
        zy_bf, W_out, MROWS, DMODEL, DINNER, nullptr, nullptr, out, x, 0);
}

// Round 8
// 500.556 us; speedup vs baseline: 5.8962x; 1.0929x over previous
//
#include <hip/hip_runtime.h>

// ---------------------------------------------------------------------------
// Mamba block. fp32 in/out. Internal: bf16 MFMA operands, fp32 accumulation
// and scan state.
// R8: big GEMMs restructured to m97-style async staging:
//   - weights pre-converted to bf16 (w2bf) into dead ws windows
//   - global_load_lds width=16 for A and B (unpadded LDS, lane-ordered)
//   - GEMM2 uses BN=64 -> 512 blocks (2/CU) to fix 1-block/CU latency bind
// ---------------------------------------------------------------------------
#define BATCH   2
#define SEQ     2048
#define DMODEL  1024
#define DINNER  2048
#define DSTATE  16
#define DTRANK  64
#define MROWS   (BATCH * SEQ)   // 4096
#define CLEN    64              // scan chunk length
#define CHUNKS  (SEQ / CLEN)    // 32

typedef float floatx4 __attribute__((ext_vector_type(4)));
typedef __bf16 bf16x8 __attribute__((ext_vector_type(8)));

__device__ __forceinline__ void async_cp16(void* lds, const void* g) {
    __builtin_amdgcn_global_load_lds((const __attribute__((address_space(1))) void*)g,
                                     (__attribute__((address_space(3))) void*)lds, 16, 0, 0);
}

// ---------------------------------------------------------------------------
// K0: fp32 -> bf16 weight conversion (grid-stride over n/4 float4 chunks)
// ---------------------------------------------------------------------------
__global__ __launch_bounds__(256) void w2bf(const float* __restrict__ w,
                                            __bf16* __restrict__ o, int n) {
    int i = (blockIdx.x * 256 + threadIdx.x) * 4;
    if (i < n) {
        floatx4 v = *(const floatx4*)&w[i];
        __bf16 r[4];
#pragma unroll
        for (int t = 0; t < 4; ++t) r[t] = (__bf16)v[t];
        *(unsigned long long*)&o[i] = *(unsigned long long*)r;
    }
}

// ---------------------------------------------------------------------------
// K1: LayerNorm.  One block per row of 1024.  fp32 in, bf16 out (GEMM A-op).
// ---------------------------------------------------------------------------
__global__ __launch_bounds__(256) void ln_kernel(const float* __restrict__ x,
                                                 const float* __restrict__ w,
                                                 const float* __restrict__ b,
                                                 __bf16* __restrict__ xn) {
    int row = blockIdx.x;
    const float* xr = x + (size_t)row * DMODEL;
    float v[4], s = 0.f, ss = 0.f;
#pragma unroll
    for (int i = 0; i < 4; ++i) {
        v[i] = xr[threadIdx.x + i * 256];
        s += v[i]; ss += v[i] * v[i];
    }
#pragma unroll
    for (int o = 32; o > 0; o >>= 1) { s += __shfl_xor(s, o); ss += __shfl_xor(ss, o); }
    __shared__ float ps[4], pss[4];
    int wv = threadIdx.x >> 6;
    if ((threadIdx.x & 63) == 0) { ps[wv] = s; pss[wv] = ss; }
    __syncthreads();
    s  = ps[0] + ps[1] + ps[2] + ps[3];
    ss = pss[0] + pss[1] + pss[2] + pss[3];
    float mu  = s * (1.f / DMODEL);
    float var = ss * (1.f / DMODEL) - mu * mu;
    float rs  = rsqrtf(var + 1e-5f);
#pragma unroll
    for (int i = 0; i < 4; ++i) {
        int c = threadIdx.x + i * 256;
        xn[(size_t)row * DMODEL + c] = (__bf16)((v[i] - mu) * rs * w[c] + b[c]);
    }
}

// ---------------------------------------------------------------------------
// K2: async-staged MFMA GEMM.  C[M,N] = A[M,K] * B[N,K]^T, A,B bf16.
// Tile 128 x (NW*32), BK=32, 4 waves (2x2), wave = 64m x (NW*16)n.
// Staging: global_load_lds 16B/lane; chunk = 1 KiB = 16 rows x 64 B, LDS
// unpadded [rows][32] so lane-linear dest == row-major tile (verified:
// dest elem = c*512 + lane*8 == (c*16 + lane/4)*32 + (lane%4)*8).
// EPI=1: split -> out0 bf16 (n<split) / out1 bf16 (n>=split)
// EPI=2: residual -> outf fp32 = acc + add[idx]
// ---------------------------------------------------------------------------
template <int EPI, int NW>
__global__ __launch_bounds__(256) void gemm_as(const __bf16* __restrict__ A,
                                               const __bf16* __restrict__ Bb,
                                               int M, int N, int K,
                                               __bf16* __restrict__ out0,
                                               __bf16* __restrict__ out1,
                                               float* __restrict__ outf,
                                               const float* __restrict__ add,
                                               int split) {
    constexpr int BNT = NW * 32;
    constexpr int NCH = 8 + BNT / 16;            // 1-KiB chunks per K-step
    __shared__ __align__(16) __bf16 sA[128 * 32];
    __shared__ __align__(16) __bf16 sB[BNT * 32];
    int tid  = threadIdx.x;
    int wave = tid >> 6, lane = tid & 63;
    int m0 = blockIdx.y * 128, n0 = blockIdx.x * BNT;
    int wm = (wave & 1) * 64, wn = (wave >> 1) * (NW * 16);
    int lr = lane & 15;
    int lq = lane >> 4;
    int r16 = lane >> 2;                         // row within a chunk
    int c8  = (lane & 3) * 8;                    // col (elements)

    floatx4 acc[4][NW] = {};

    for (int k0 = 0; k0 < K; k0 += 32) {
        for (int c = wave; c < NCH; c += 4) {
            if (c < 8) {
                const __bf16* g = A + (size_t)(m0 + c * 16 + r16) * K + k0 + c8;
                async_cp16(&sA[c * 512], g);
            } else {
                int cb = c - 8;
                const __bf16* g = Bb + (size_t)(n0 + cb * 16 + r16) * K + k0 + c8;
                async_cp16(&sB[cb * 512], g);
            }
        }
        __syncthreads();                          // compiler drains vmcnt here

        bf16x8 af[4], bfr[NW];
#pragma unroll
        for (int i = 0; i < 4; ++i)  af[i]  = *(const bf16x8*)&sA[(wm + i * 16 + lr) * 32 + lq * 8];
#pragma unroll
        for (int j = 0; j < NW; ++j) bfr[j] = *(const bf16x8*)&sB[(wn + j * 16 + lr) * 32 + lq * 8];
#pragma unroll
        for (int i = 0; i < 4; ++i)
#pragma unroll
            for (int j = 0; j < NW; ++j)
                acc[i][j] = __builtin_amdgcn_mfma_f32_16x16x32_bf16(af[i], bfr[j], acc[i][j], 0, 0, 0);
        __syncthreads();
    }

#pragma unroll
    for (int i = 0; i < 4; ++i)
#pragma unroll
        for (int j = 0; j < NW; ++j) {
            int gn = n0 + wn + j * 16 + lr;
#pragma unroll
            for (int r = 0; r < 4; ++r) {
                int gm = m0 + wm + i * 16 + lq * 4 + r;
                float v = acc[i][j][r];
                if (EPI == 1) {
                    if (gn < split) out0[(size_t)gm * split + gn] = (__bf16)v;
                    else            out1[(size_t)gm * split + (gn - split)] = (__bf16)v;
                } else {
                    size_t idx = (size_t)gm * N + gn;
                    outf[idx] = v + add[idx];
                }
            }
        }
}

// ---------------------------------------------------------------------------
// K3: depthwise causal conv (width 4) + bias + SiLU.
// ---------------------------------------------------------------------------
__global__ __launch_bounds__(256) void conv_kernel(const __bf16* __restrict__ xin,
                                                   const float* __restrict__ cw,
                                                   const float* __restrict__ cb,
                                                   __bf16* __restrict__ u) {
    int idx = blockIdx.x * 256 + threadIdx.x;        // over MROWS*DINNER
    int d  = idx & (DINNER - 1);
    int bl = idx >> 11;                              // b*SEQ + l
    int l  = bl & (SEQ - 1);
    float acc = cb[d];
#pragma unroll
    for (int j = 0; j < 4; ++j) {
        int ll = l - 3 + j;
        if (ll >= 0) acc += (float)xin[(size_t)(bl - 3 + j) * DINNER + d] * cw[d * 4 + j];
    }
    float sg = 1.f / (1.f + __expf(-acc));
    u[idx] = (__bf16)(acc * sg);
}

// ---------------------------------------------------------------------------
// K4 (MFMA): xdbl[4096,96] = u[4096,2048] @ Wx[96,2048]^T, fp32 out.
// BM=128 x BN=96; 4 waves 2x2, each 64x48 (acc[4][3]); full K per block.
// ---------------------------------------------------------------------------
#define BM 128
#define BN 128
#define BK 32
#define LDK 48

__global__ __launch_bounds__(256) void wx_mfma(const __bf16* __restrict__ A,
                                               const float* __restrict__ B,
                                               float* __restrict__ xdbl) {
    __shared__ __align__(16) __bf16 sA[BM][LDK];
    __shared__ __align__(16) __bf16 sB[96][LDK];
    int tid  = threadIdx.x;
    int wave = tid >> 6, lane = tid & 63;
    int m0 = blockIdx.x * BM;
    int wm = (wave & 1) * 64, wn = (wave >> 1) * 48;
    int lr = lane & 15;
    int lq = lane >> 4;

    floatx4 acc[4][3] = {};

    for (int k0 = 0; k0 < DINNER; k0 += BK) {
#pragma unroll
        for (int c = tid; c < 512; c += 256) {
            int row = c >> 2, col = (c & 3) * 8;
            *(bf16x8*)&sA[row][col] = *(const bf16x8*)&A[(size_t)(m0 + row) * DINNER + k0 + col];
        }
        for (int c = tid; c < 384; c += 256) {
            int row = c >> 2, col = (c & 3) * 8;
            const float* src = B + (size_t)row * DINNER + k0 + col;
            floatx4 lo = *(const floatx4*)src;
            floatx4 hi = *(const floatx4*)(src + 4);
            bf16x8 v;
#pragma unroll
            for (int t = 0; t < 4; ++t) { v[t] = (__bf16)lo[t]; v[4 + t] = (__bf16)hi[t]; }
            *(bf16x8*)&sB[row][col] = v;
        }
        __syncthreads();

        bf16x8 af[4], bfr[3];
#pragma unroll
        for (int i = 0; i < 4; ++i) af[i]  = *(const bf16x8*)&sA[wm + i * 16 + lr][lq * 8];
#pragma unroll
        for (int j = 0; j < 3; ++j) bfr[j] = *(const bf16x8*)&sB[wn + j * 16 + lr][lq * 8];
#pragma unroll
        for (int i = 0; i < 4; ++i)
#pragma unroll
            for (int j = 0; j < 3; ++j)
                acc[i][j] = __builtin_amdgcn_mfma_f32_16x16x32_bf16(af[i], bfr[j], acc[i][j], 0, 0, 0);
        __syncthreads();
    }

#pragma unroll
    for (int i = 0; i < 4; ++i)
#pragma unroll
        for (int j = 0; j < 3; ++j) {
            int gn = wn + j * 16 + lr;
#pragma unroll
            for (int r = 0; r < 4; ++r) {
                int gm = m0 + wm + i * 16 + lq * 4 + r;
                xdbl[(size_t)gm * 96 + gn] = acc[i][j][r];
            }
        }
}

// ---------------------------------------------------------------------------
// K5 (MFMA): dt[4096,2048] = softplus(xdbl[:,0:64] @ Wdt[2048,64]^T + b_dt)
// ---------------------------------------------------------------------------
__global__ __launch_bounds__(256) void dt_mfma(const float* __restrict__ Af,
                                               const float* __restrict__ B,
                                               const float* __restrict__ bdt,
                                               __bf16* __restrict__ dt) {
    __shared__ __align__(16) __bf16 sA[BM][LDK];
    __shared__ __align__(16) __bf16 sB[BN][LDK];
    int tid  = threadIdx.x;
    int wave = tid >> 6, lane = tid & 63;
    int m0 = blockIdx.y * BM, n0 = blockIdx.x * BN;
    int wm = (wave & 1) * 64, wn = (wave >> 1) * 64;
    int lr = lane & 15;
    int lq = lane >> 4;

    floatx4 acc[4][4] = {};

    for (int k0 = 0; k0 < DTRANK; k0 += BK) {
#pragma unroll
        for (int c = tid; c < 512; c += 256) {
            int row = c >> 2, col = (c & 3) * 8;
            const float* src = Af + (size_t)(m0 + row) * 96 + k0 + col;
            floatx4 lo = *(const floatx4*)src;
            floatx4 hi = *(const floatx4*)(src + 4);
            bf16x8 v;
#pragma unroll
            for (int t = 0; t < 4; ++t) { v[t] = (__bf16)lo[t]; v[4 + t] = (__bf16)hi[t]; }
            *(bf16x8*)&sA[row][col] = v;
        }
#pragma unroll
        for (int c = tid; c < 512; c += 256) {
            int row = c >> 2, col = (c & 3) * 8;
            const float* src = B + (size_t)(n0 + row) * DTRANK + k0 + col;
            floatx4 lo = *(const floatx4*)src;
            floatx4 hi = *(const floatx4*)(src + 4);
            bf16x8 v;
#pragma unroll
            for (int t = 0; t < 4; ++t) { v[t] = (__bf16)lo[t]; v[4 + t] = (__bf16)hi[t]; }
            *(bf16x8*)&sB[row][col] = v;
        }
        __syncthreads();

        bf16x8 af[4], bfr[4];
#pragma unroll
        for (int i = 0; i < 4; ++i) af[i]  = *(const bf16x8*)&sA[wm + i * 16 + lr][lq * 8];
#pragma unroll
        for (int j = 0; j < 4; ++j) bfr[j] = *(const bf16x8*)&sB[wn + j * 16 + lr][lq * 8];
#pragma unroll
        for (int i = 0; i < 4; ++i)
#pragma unroll
            for (int j = 0; j < 4; ++j)
                acc[i][j] = __builtin_amdgcn_mfma_f32_16x16x32_bf16(af[i], bfr[j], acc[i][j], 0, 0, 0);
        __syncthreads();
    }

#pragma unroll
    for (int i = 0; i < 4; ++i)
#pragma unroll
        for (int j = 0; j < 4; ++j) {
            int gn = n0 + wn + j * 16 + lr;
            float bv = bdt[gn];
#pragma unroll
            for (int r = 0; r < 4; ++r) {
                int gm = m0 + wm + i * 16 + lq * 4 + r;
                float a = acc[i][j][r] + bv;
                float sp = (a > 20.f) ? a : log1pf(__expf(a));
                dt[(size_t)gm * DINNER + gn] = (__bf16)sp;
            }
        }
}

// ---------------------------------------------------------------------------
// K6 (3-pass chunked scan).  h_t = exp(dt_t*A)*h_{t-1} + dt_t*u_t*B_t.
// ---------------------------------------------------------------------------
__global__ __launch_bounds__(64) void scan_pass1(const __bf16* __restrict__ dt,
                                                 const __bf16* __restrict__ u,
                                                 const float* __restrict__ xdbl,
                                                 const float* __restrict__ Alog,
                                                 float* __restrict__ Sdt,
                                                 __bf16* __restrict__ Hfix) {
    int c = blockIdx.x, dblk = blockIdx.y, b = blockIdx.z;
    int lane = threadIdx.x;
    int d0 = dblk * 64, d = d0 + lane;
    int row0 = b * SEQ + c * CLEN;

    __shared__ __align__(16) __bf16 sdt[CLEN][64];
    __shared__ __align__(16) __bf16 su [CLEN][64];
    __shared__ __align__(16) float  sB [CLEN][DSTATE];

#pragma unroll
    for (int i = 0; i < 32; ++i) {
        int idx = i * 64 + lane, t = idx >> 5, p = idx & 31;
        ((unsigned*)&sdt[t][0])[p] = *(const unsigned*)(dt + (size_t)(row0 + t) * DINNER + d0 + p * 2);
        ((unsigned*)&su [t][0])[p] = *(const unsigned*)(u  + (size_t)(row0 + t) * DINNER + d0 + p * 2);
    }
#pragma unroll
    for (int i = 0; i < 4; ++i) {
        int idx = i * 64 + lane, t = idx >> 2, q = idx & 3;
        *(floatx4*)&sB[t][q * 4] = *(const floatx4*)&xdbl[(size_t)(row0 + t) * 96 + 64 + q * 4];
    }
    __syncthreads();

    float A[DSTATE], h[DSTATE];
#pragma unroll
    for (int s = 0; s < DSTATE; ++s) { A[s] = -__expf(Alog[d * DSTATE + s]); h[s] = 0.f; }

    float S = 0.f;
    for (int t = 0; t < CLEN; ++t) {
        float dtv = (float)sdt[t][lane];
        float du  = dtv * (float)su[t][lane];
        S += dtv;
#pragma unroll
        for (int s = 0; s < DSTATE; ++s)
            h[s] = __expf(dtv * A[s]) * h[s] + du * sB[t][s];
    }
    size_t ch = ((size_t)(b * DINNER + d) * CHUNKS + c);
    Sdt[ch] = S;
#pragma unroll
    for (int s = 0; s < DSTATE; ++s) Hfix[ch * DSTATE + s] = (__bf16)h[s];
}

__global__ __launch_bounds__(256) void scan_pass2(const float* __restrict__ Alog,
                                                  const float* __restrict__ Sdt,
                                                  __bf16* __restrict__ Hfix) {
    int g = blockIdx.x * 256 + threadIdx.x;       // over BATCH*DINNER*DSTATE
    int s = g & (DSTATE - 1);
    int bd = g >> 4;
    int d = bd & (DINNER - 1);
    float A = -__expf(Alog[d * DSTATE + s]);
    size_t hbase = (size_t)bd * CHUNKS * DSTATE + s;
    size_t sbase = (size_t)bd * CHUNKS;
    float h = 0.f;
#pragma unroll 4
    for (int c = 0; c < CHUNKS; ++c) {
        float Hl = (float)Hfix[hbase + c * DSTATE];
        float P  = __expf(A * Sdt[sbase + c]);
        Hfix[hbase + c * DSTATE] = (__bf16)h;
        h = P * h + Hl;
    }
}

__global__ __launch_bounds__(64) void scan_pass3(const __bf16* __restrict__ dt,
                                                 const __bf16* __restrict__ u,
                                                 const float* __restrict__ xdbl,
                                                 const float* __restrict__ Alog,
                                                 const float* __restrict__ Dp,
                                                 const __bf16* __restrict__ Hfix,
                                                 __bf16* zy) {
    int c = blockIdx.x, dblk = blockIdx.y, b = blockIdx.z;
    int lane = threadIdx.x;
    int d0 = dblk * 64, d = d0 + lane;
    int row0 = b * SEQ + c * CLEN;

    __shared__ __align__(16) __bf16 sdt[CLEN][64];
    __shared__ __align__(16) __bf16 su [CLEN][64];
    __shared__ __align__(16) __bf16 sz [CLEN][64];
    __shared__ __align__(16) float  sBC[CLEN][2 * DSTATE];

#pragma unroll
    for (int i = 0; i < 32; ++i) {
        int idx = i * 64 + lane, t = idx >> 5, p = idx & 31;
        ((unsigned*)&sdt[t][0])[p] = *(const unsigned*)(dt + (size_t)(row0 + t) * DINNER + d0 + p * 2);
        ((unsigned*)&su [t][0])[p] = *(const unsigned*)(u  + (size_t)(row0 + t) * DINNER + d0 + p * 2);
        ((unsigned*)&sz [t][0])[p] = *(const unsigned*)((const __bf16*)zy + (size_t)(row0 + t) * DINNER + d0 + p * 2);
    }
#pragma unroll
    for (int i = 0; i < 8; ++i) {
        int idx = i * 64 + lane, t = idx >> 3, q = idx & 7;
        *(floatx4*)&sBC[t][q * 4] = *(const floatx4*)&xdbl[(size_t)(row0 + t) * 96 + 64 + q * 4];
    }
    __syncthreads();

    float A[DSTATE], h[DSTATE];
    size_t ch = ((size_t)(b * DINNER + d) * CHUNKS + c);
#pragma unroll
    for (int s = 0; s < DSTATE; ++s) {
        A[s] = -__expf(Alog[d * DSTATE + s]);
        h[s] = (float)Hfix[ch * DSTATE + s];
    }
    float Dv = Dp[d];

    for (int t = 0; t < CLEN; ++t) {
        float dtv = (float)sdt[t][lane];
        float uv  = (float)su[t][lane];
        float du  = dtv * uv;
        float yv  = 0.f;
#pragma unroll
        for (int s = 0; s < DSTATE; ++s) {
            h[s] = __expf(dtv * A[s]) * h[s] + du * sBC[t][s];
            yv  += h[s] * sBC[t][DSTATE + s];
        }
        float zv = (float)sz[t][lane];
        float sg = zv / (1.f + __expf(-zv));
        zy[(size_t)(row0 + t) * DINNER + d] = (__bf16)((yv + uv * Dv) * sg);
    }
}

// ---------------------------------------------------------------------------
extern "C" void kernel_launch(void* const* d_in, const int* in_sizes, int n_in,
                              void* d_out, int out_size, void* d_ws, size_t ws_size,
                              hipStream_t stream) {
    const float* x      = (const float*)d_in[0];
    const float* ln_w   = (const float*)d_in[1];
    const float* ln_b   = (const float*)d_in[2];
    const float* W_in   = (const float*)d_in[3];
    const float* conv_w = (const float*)d_in[4];
    const float* conv_b = (const float*)d_in[5];
    const float* W_x    = (const float*)d_in[6];
    const float* W_dt   = (const float*)d_in[7];
    const float* b_dt   = (const float*)d_in[8];
    const float* A_log  = (const float*)d_in[9];
    const float* Dp     = (const float*)d_in[10];
    const float* W_out  = (const float*)d_in[11];
    float* out = (float*)d_out;

    // Workspace, 56 MiB peak:
    //   [ 0,  8M)  xn bf16 (dead after GEMM1) -> { xdbl fp32 [0,1.5M),
    //              Sdt fp32 [1.5M,2M), Hfix bf16 [2M,6M) }
    //   [ 8M,24M)  x_in bf16 (dead after conv) -> dt bf16
    //   [24M,40M)  z bf16; scan pass3 overwrites with y in place
    //   [40M,56M)  Winb bf16 8M (dead after GEMM1) -> u bf16 16M (conv..pass3)
    //              -> Woutb bf16 4M (after pass3)
    char* ws = (char*)d_ws;
    __bf16* xn_bf  = (__bf16*)(ws);
    float*  xdbl   = (float*) (ws);
    float*  Sdt    = (float*) (ws + 1536ull * 1024);
    __bf16* Hfix   = (__bf16*)(ws + (2ull  << 20));
    __bf16* xin_bf = (__bf16*)(ws + (8ull  << 20));
    __bf16* dt_bf  = (__bf16*)(ws + (8ull  << 20));
    __bf16* zy_bf  = (__bf16*)(ws + (24ull << 20));
    __bf16* Winb   = (__bf16*)(ws + (40ull << 20));
    __bf16* u_bf   = (__bf16*)(ws + (40ull << 20));
    __bf16* Woutb  = (__bf16*)(ws + (40ull << 20));

    ln_kernel<<<MROWS, 256, 0, stream>>>(x, ln_w, ln_b, xn_bf);

    w2bf<<<(2 * DINNER * DMODEL) / 1024, 256, 0, stream>>>(W_in, Winb, 2 * DINNER * DMODEL);

    gemm_as<1, 4><<<dim3(2 * DINNER / 128, MROWS / 128), 256, 0, stream>>>(
        xn_bf, Winb, MROWS, 2 * DINNER, DMODEL, xin_bf, zy_bf, nullptr, nullptr, DINNER);

    conv_kernel<<<MROWS * DINNER / 256, 256, 0, stream>>>(xin_bf, conv_w, conv_b, u_bf);

    wx_mfma<<<MROWS / BM, 256, 0, stream>>>(u_bf, W_x, xdbl);

    dt_mfma<<<dim3(DINNER / BN, MROWS / BM), 256, 0, stream>>>(xdbl, W_dt, b_dt, dt_bf);

    dim3 sgrid(CHUNKS, DINNER / 64, BATCH);
    scan_pass1<<<sgrid, 64, 0, stream>>>(dt_bf, u_bf, xdbl, A_log, Sdt, Hfix);
    scan_pass2<<<BATCH * DINNER * DSTATE / 256, 256, 0, stream>>>(A_log, Sdt, Hfix);
    scan_pass3<<<sgrid, 64, 0, stream>>>(dt_bf, u_bf, xdbl, A_log, Dp, Hfix, zy_bf);

    w2bf<<<(DMODEL * DINNER) / 1024, 256, 0, stream>>>(W_out, Woutb, DMODEL * DINNER);

    gemm_as<2, 2><<<dim3(DMODEL / 64, MROWS / 128), 256, 0, stream>>>(
        zy_bf, Woutb, MROWS, DMODEL, DINNER, nullptr, nullptr, out, x, 0);
}

// Round 9
// 447.343 us; speedup vs baseline: 6.5975x; 1.1190x over previous
//
#include <hip/hip_runtime.h>

// ---------------------------------------------------------------------------
// Mamba block. fp32 in/out. Internal: bf16 MFMA operands, fp32 accumulation
// and scan state.
// R9: wx_mfma was 102 us at 1.4% occupancy (32 blocks on 256 CUs). Now
// split-K: grid (32 m-blocks, 16 k-slices) = 512 blocks, fp32 atomic
// accumulation into zeroed xdbl.
// ---------------------------------------------------------------------------
#define BATCH   2
#define SEQ     2048
#define DMODEL  1024
#define DINNER  2048
#define DSTATE  16
#define DTRANK  64
#define MROWS   (BATCH * SEQ)   // 4096
#define CLEN    64              // scan chunk length
#define CHUNKS  (SEQ / CLEN)    // 32

typedef float floatx4 __attribute__((ext_vector_type(4)));
typedef __bf16 bf16x8 __attribute__((ext_vector_type(8)));

__device__ __forceinline__ void async_cp16(void* lds, const void* g) {
    __builtin_amdgcn_global_load_lds((const __attribute__((address_space(1))) void*)g,
                                     (__attribute__((address_space(3))) void*)lds, 16, 0, 0);
}

// ---------------------------------------------------------------------------
// K0: fp32 -> bf16 weight conversion
// ---------------------------------------------------------------------------
__global__ __launch_bounds__(256) void w2bf(const float* __restrict__ w,
                                            __bf16* __restrict__ o, int n) {
    int i = (blockIdx.x * 256 + threadIdx.x) * 4;
    if (i < n) {
        floatx4 v = *(const floatx4*)&w[i];
        __bf16 r[4];
#pragma unroll
        for (int t = 0; t < 4; ++t) r[t] = (__bf16)v[t];
        *(unsigned long long*)&o[i] = *(unsigned long long*)r;
    }
}

// ---------------------------------------------------------------------------
// K1: LayerNorm.  One block per row of 1024.  fp32 in, bf16 out (GEMM A-op).
// ---------------------------------------------------------------------------
__global__ __launch_bounds__(256) void ln_kernel(const float* __restrict__ x,
                                                 const float* __restrict__ w,
                                                 const float* __restrict__ b,
                                                 __bf16* __restrict__ xn) {
    int row = blockIdx.x;
    const float* xr = x + (size_t)row * DMODEL;
    float v[4], s = 0.f, ss = 0.f;
#pragma unroll
    for (int i = 0; i < 4; ++i) {
        v[i] = xr[threadIdx.x + i * 256];
        s += v[i]; ss += v[i] * v[i];
    }
#pragma unroll
    for (int o = 32; o > 0; o >>= 1) { s += __shfl_xor(s, o); ss += __shfl_xor(ss, o); }
    __shared__ float ps[4], pss[4];
    int wv = threadIdx.x >> 6;
    if ((threadIdx.x & 63) == 0) { ps[wv] = s; pss[wv] = ss; }
    __syncthreads();
    s  = ps[0] + ps[1] + ps[2] + ps[3];
    ss = pss[0] + pss[1] + pss[2] + pss[3];
    float mu  = s * (1.f / DMODEL);
    float var = ss * (1.f / DMODEL) - mu * mu;
    float rs  = rsqrtf(var + 1e-5f);
#pragma unroll
    for (int i = 0; i < 4; ++i) {
        int c = threadIdx.x + i * 256;
        xn[(size_t)row * DMODEL + c] = (__bf16)((v[i] - mu) * rs * w[c] + b[c]);
    }
}

// ---------------------------------------------------------------------------
// K2: async-staged MFMA GEMM.  C[M,N] = A[M,K] * B[N,K]^T, A,B bf16.
// Tile 128 x (NW*32), BK=32, 4 waves (2x2), wave = 64m x (NW*16)n.
// EPI=1: split -> out0 bf16 (n<split) / out1 bf16 (n>=split)
// EPI=2: residual -> outf fp32 = acc + add[idx]
// ---------------------------------------------------------------------------
template <int EPI, int NW>
__global__ __launch_bounds__(256) void gemm_as(const __bf16* __restrict__ A,
                                               const __bf16* __restrict__ Bb,
                                               int M, int N, int K,
                                               __bf16* __restrict__ out0,
                                               __bf16* __restrict__ out1,
                                               float* __restrict__ outf,
                                               const float* __restrict__ add,
                                               int split) {
    constexpr int BNT = NW * 32;
    constexpr int NCH = 8 + BNT / 16;            // 1-KiB chunks per K-step
    __shared__ __align__(16) __bf16 sA[128 * 32];
    __shared__ __align__(16) __bf16 sB[BNT * 32];
    int tid  = threadIdx.x;
    int wave = tid >> 6, lane = tid & 63;
    int m0 = blockIdx.y * 128, n0 = blockIdx.x * BNT;
    int wm = (wave & 1) * 64, wn = (wave >> 1) * (NW * 16);
    int lr = lane & 15;
    int lq = lane >> 4;
    int r16 = lane >> 2;                         // row within a chunk
    int c8  = (lane & 3) * 8;                    // col (elements)

    floatx4 acc[4][NW] = {};

    for (int k0 = 0; k0 < K; k0 += 32) {
        for (int c = wave; c < NCH; c += 4) {
            if (c < 8) {
                const __bf16* g = A + (size_t)(m0 + c * 16 + r16) * K + k0 + c8;
                async_cp16(&sA[c * 512], g);
            } else {
                int cb = c - 8;
                const __bf16* g = Bb + (size_t)(n0 + cb * 16 + r16) * K + k0 + c8;
                async_cp16(&sB[cb * 512], g);
            }
        }
        __syncthreads();

        bf16x8 af[4], bfr[NW];
#pragma unroll
        for (int i = 0; i < 4; ++i)  af[i]  = *(const bf16x8*)&sA[(wm + i * 16 + lr) * 32 + lq * 8];
#pragma unroll
        for (int j = 0; j < NW; ++j) bfr[j] = *(const bf16x8*)&sB[(wn + j * 16 + lr) * 32 + lq * 8];
#pragma unroll
        for (int i = 0; i < 4; ++i)
#pragma unroll
            for (int j = 0; j < NW; ++j)
                acc[i][j] = __builtin_amdgcn_mfma_f32_16x16x32_bf16(af[i], bfr[j], acc[i][j], 0, 0, 0);
        __syncthreads();
    }

#pragma unroll
    for (int i = 0; i < 4; ++i)
#pragma unroll
        for (int j = 0; j < NW; ++j) {
            int gn = n0 + wn + j * 16 + lr;
#pragma unroll
            for (int r = 0; r < 4; ++r) {
                int gm = m0 + wm + i * 16 + lq * 4 + r;
                float v = acc[i][j][r];
                if (EPI == 1) {
                    if (gn < split) out0[(size_t)gm * split + gn] = (__bf16)v;
                    else            out1[(size_t)gm * split + (gn - split)] = (__bf16)v;
                } else {
                    size_t idx = (size_t)gm * N + gn;
                    outf[idx] = v + add[idx];
                }
            }
        }
}

// ---------------------------------------------------------------------------
// K3: depthwise causal conv (width 4) + bias + SiLU.
// ---------------------------------------------------------------------------
__global__ __launch_bounds__(256) void conv_kernel(const __bf16* __restrict__ xin,
                                                   const float* __restrict__ cw,
                                                   const float* __restrict__ cb,
                                                   __bf16* __restrict__ u) {
    int idx = blockIdx.x * 256 + threadIdx.x;        // over MROWS*DINNER
    int d  = idx & (DINNER - 1);
    int bl = idx >> 11;                              // b*SEQ + l
    int l  = bl & (SEQ - 1);
    float acc = cb[d];
#pragma unroll
    for (int j = 0; j < 4; ++j) {
        int ll = l - 3 + j;
        if (ll >= 0) acc += (float)xin[(size_t)(bl - 3 + j) * DINNER + d] * cw[d * 4 + j];
    }
    float sg = 1.f / (1.f + __expf(-acc));
    u[idx] = (__bf16)(acc * sg);
}

// ---------------------------------------------------------------------------
// K4 (MFMA, split-K): xdbl[4096,96] += u[4096,2048] @ Wx[96,2048]^T.
// Grid (MROWS/128, WX_KS).  Each block: 128x96 tile over a K-slice of
// DINNER/WX_KS, atomically accumulated (HW global_atomic_add_f32) into
// zero-initialized xdbl.  Fixes R8's 1.4%-occupancy latency bind (32 blocks).
// ---------------------------------------------------------------------------
#define BM 128
#define BN 128
#define BK 32
#define LDK 48
#define WX_KS 16
#define WX_KSLICE (DINNER / WX_KS)   // 128

__global__ __launch_bounds__(256) void wx_mfma(const __bf16* __restrict__ A,
                                               const float* __restrict__ B,
                                               float* __restrict__ xdbl) {
    __shared__ __align__(16) __bf16 sA[BM][LDK];
    __shared__ __align__(16) __bf16 sB[96][LDK];
    int tid  = threadIdx.x;
    int wave = tid >> 6, lane = tid & 63;
    int m0 = blockIdx.x * BM;
    int k0base = blockIdx.y * WX_KSLICE;
    int wm = (wave & 1) * 64, wn = (wave >> 1) * 48;
    int lr = lane & 15;
    int lq = lane >> 4;

    floatx4 acc[4][3] = {};

    for (int k0 = k0base; k0 < k0base + WX_KSLICE; k0 += BK) {
#pragma unroll
        for (int c = tid; c < 512; c += 256) {
            int row = c >> 2, col = (c & 3) * 8;
            *(bf16x8*)&sA[row][col] = *(const bf16x8*)&A[(size_t)(m0 + row) * DINNER + k0 + col];
        }
        for (int c = tid; c < 384; c += 256) {
            int row = c >> 2, col = (c & 3) * 8;
            const float* src = B + (size_t)row * DINNER + k0 + col;
            floatx4 lo = *(const floatx4*)src;
            floatx4 hi = *(const floatx4*)(src + 4);
            bf16x8 v;
#pragma unroll
            for (int t = 0; t < 4; ++t) { v[t] = (__bf16)lo[t]; v[4 + t] = (__bf16)hi[t]; }
            *(bf16x8*)&sB[row][col] = v;
        }
        __syncthreads();

        bf16x8 af[4], bfr[3];
#pragma unroll
        for (int i = 0; i < 4; ++i) af[i]  = *(const bf16x8*)&sA[wm + i * 16 + lr][lq * 8];
#pragma unroll
        for (int j = 0; j < 3; ++j) bfr[j] = *(const bf16x8*)&sB[wn + j * 16 + lr][lq * 8];
#pragma unroll
        for (int i = 0; i < 4; ++i)
#pragma unroll
            for (int j = 0; j < 3; ++j)
                acc[i][j] = __builtin_amdgcn_mfma_f32_16x16x32_bf16(af[i], bfr[j], acc[i][j], 0, 0, 0);
        __syncthreads();
    }

#pragma unroll
    for (int i = 0; i < 4; ++i)
#pragma unroll
        for (int j = 0; j < 3; ++j) {
            int gn = wn + j * 16 + lr;
#pragma unroll
            for (int r = 0; r < 4; ++r) {
                int gm = m0 + wm + i * 16 + lq * 4 + r;
                unsafeAtomicAdd(&xdbl[(size_t)gm * 96 + gn], acc[i][j][r]);
            }
        }
}

// ---------------------------------------------------------------------------
// K5 (MFMA): dt[4096,2048] = softplus(xdbl[:,0:64] @ Wdt[2048,64]^T + b_dt)
// ---------------------------------------------------------------------------
__global__ __launch_bounds__(256) void dt_mfma(const float* __restrict__ Af,
                                               const float* __restrict__ B,
                                               const float* __restrict__ bdt,
                                               __bf16* __restrict__ dt) {
    __shared__ __align__(16) __bf16 sA[BM][LDK];
    __shared__ __align__(16) __bf16 sB[BN][LDK];
    int tid  = threadIdx.x;
    int wave = tid >> 6, lane = tid & 63;
    int m0 = blockIdx.y * BM, n0 = blockIdx.x * BN;
    int wm = (wave & 1) * 64, wn = (wave >> 1) * 64;
    int lr = lane & 15;
    int lq = lane >> 4;

    floatx4 acc[4][4] = {};

    for (int k0 = 0; k0 < DTRANK; k0 += BK) {
#pragma unroll
        for (int c = tid; c < 512; c += 256) {
            int row = c >> 2, col = (c & 3) * 8;
            const float* src = Af + (size_t)(m0 + row) * 96 + k0 + col;
            floatx4 lo = *(const floatx4*)src;
            floatx4 hi = *(const floatx4*)(src + 4);
            bf16x8 v;
#pragma unroll
            for (int t = 0; t < 4; ++t) { v[t] = (__bf16)lo[t]; v[4 + t] = (__bf16)hi[t]; }
            *(bf16x8*)&sA[row][col] = v;
        }
#pragma unroll
        for (int c = tid; c < 512; c += 256) {
            int row = c >> 2, col = (c & 3) * 8;
            const float* src = B + (size_t)(n0 + row) * DTRANK + k0 + col;
            floatx4 lo = *(const floatx4*)src;
            floatx4 hi = *(const floatx4*)(src + 4);
            bf16x8 v;
#pragma unroll
            for (int t = 0; t < 4; ++t) { v[t] = (__bf16)lo[t]; v[4 + t] = (__bf16)hi[t]; }
            *(bf16x8*)&sB[row][col] = v;
        }
        __syncthreads();

        bf16x8 af[4], bfr[4];
#pragma unroll
        for (int i = 0; i < 4; ++i) af[i]  = *(const bf16x8*)&sA[wm + i * 16 + lr][lq * 8];
#pragma unroll
        for (int j = 0; j < 4; ++j) bfr[j] = *(const bf16x8*)&sB[wn + j * 16 + lr][lq * 8];
#pragma unroll
        for (int i = 0; i < 4; ++i)
#pragma unroll
            for (int j = 0; j < 4; ++j)
                acc[i][j] = __builtin_amdgcn_mfma_f32_16x16x32_bf16(af[i], bfr[j], acc[i][j], 0, 0, 0);
        __syncthreads();
    }

#pragma unroll
    for (int i = 0; i < 4; ++i)
#pragma unroll
        for (int j = 0; j < 4; ++j) {
            int gn = n0 + wn + j * 16 + lr;
            float bv = bdt[gn];
#pragma unroll
            for (int r = 0; r < 4; ++r) {
                int gm = m0 + wm + i * 16 + lq * 4 + r;
                float a = acc[i][j][r] + bv;
                float sp = (a > 20.f) ? a : log1pf(__expf(a));
                dt[(size_t)gm * DINNER + gn] = (__bf16)sp;
            }
        }
}

// ---------------------------------------------------------------------------
// K6 (3-pass chunked scan).  h_t = exp(dt_t*A)*h_{t-1} + dt_t*u_t*B_t.
// ---------------------------------------------------------------------------
__global__ __launch_bounds__(64) void scan_pass1(const __bf16* __restrict__ dt,
                                                 const __bf16* __restrict__ u,
                                                 const float* __restrict__ xdbl,
                                                 const float* __restrict__ Alog,
                                                 float* __restrict__ Sdt,
                                                 __bf16* __restrict__ Hfix) {
    int c = blockIdx.x, dblk = blockIdx.y, b = blockIdx.z;
    int lane = threadIdx.x;
    int d0 = dblk * 64, d = d0 + lane;
    int row0 = b * SEQ + c * CLEN;

    __shared__ __align__(16) __bf16 sdt[CLEN][64];
    __shared__ __align__(16) __bf16 su [CLEN][64];
    __shared__ __align__(16) float  sB [CLEN][DSTATE];

#pragma unroll
    for (int i = 0; i < 32; ++i) {
        int idx = i * 64 + lane, t = idx >> 5, p = idx & 31;
        ((unsigned*)&sdt[t][0])[p] = *(const unsigned*)(dt + (size_t)(row0 + t) * DINNER + d0 + p * 2);
        ((unsigned*)&su [t][0])[p] = *(const unsigned*)(u  + (size_t)(row0 + t) * DINNER + d0 + p * 2);
    }
#pragma unroll
    for (int i = 0; i < 4; ++i) {
        int idx = i * 64 + lane, t = idx >> 2, q = idx & 3;
        *(floatx4*)&sB[t][q * 4] = *(const floatx4*)&xdbl[(size_t)(row0 + t) * 96 + 64 + q * 4];
    }
    __syncthreads();

    float A[DSTATE], h[DSTATE];
#pragma unroll
    for (int s = 0; s < DSTATE; ++s) { A[s] = -__expf(Alog[d * DSTATE + s]); h[s] = 0.f; }

    float S = 0.f;
    for (int t = 0; t < CLEN; ++t) {
        float dtv = (float)sdt[t][lane];
        float du  = dtv * (float)su[t][lane];
        S += dtv;
#pragma unroll
        for (int s = 0; s < DSTATE; ++s)
            h[s] = __expf(dtv * A[s]) * h[s] + du * sB[t][s];
    }
    size_t ch = ((size_t)(b * DINNER + d) * CHUNKS + c);
    Sdt[ch] = S;
#pragma unroll
    for (int s = 0; s < DSTATE; ++s) Hfix[ch * DSTATE + s] = (__bf16)h[s];
}

__global__ __launch_bounds__(256) void scan_pass2(const float* __restrict__ Alog,
                                                  const float* __restrict__ Sdt,
                                                  __bf16* __restrict__ Hfix) {
    int g = blockIdx.x * 256 + threadIdx.x;       // over BATCH*DINNER*DSTATE
    int s = g & (DSTATE - 1);
    int bd = g >> 4;
    int d = bd & (DINNER - 1);
    float A = -__expf(Alog[d * DSTATE + s]);
    size_t hbase = (size_t)bd * CHUNKS * DSTATE + s;
    size_t sbase = (size_t)bd * CHUNKS;
    float h = 0.f;
#pragma unroll 4
    for (int c = 0; c < CHUNKS; ++c) {
        float Hl = (float)Hfix[hbase + c * DSTATE];
        float P  = __expf(A * Sdt[sbase + c]);
        Hfix[hbase + c * DSTATE] = (__bf16)h;
        h = P * h + Hl;
    }
}

__global__ __launch_bounds__(64) void scan_pass3(const __bf16* __restrict__ dt,
                                                 const __bf16* __restrict__ u,
                                                 const float* __restrict__ xdbl,
                                                 const float* __restrict__ Alog,
                                                 const float* __restrict__ Dp,
                                                 const __bf16* __restrict__ Hfix,
                                                 __bf16* zy) {
    int c = blockIdx.x, dblk = blockIdx.y, b = blockIdx.z;
    int lane = threadIdx.x;
    int d0 = dblk * 64, d = d0 + lane;
    int row0 = b * SEQ + c * CLEN;

    __shared__ __align__(16) __bf16 sdt[CLEN][64];
    __shared__ __align__(16) __bf16 su [CLEN][64];
    __shared__ __align__(16) __bf16 sz [CLEN][64];
    __shared__ __align__(16) float  sBC[CLEN][2 * DSTATE];

#pragma unroll
    for (int i = 0; i < 32; ++i) {
        int idx = i * 64 + lane, t = idx >> 5, p = idx & 31;
        ((unsigned*)&sdt[t][0])[p] = *(const unsigned*)(dt + (size_t)(row0 + t) * DINNER + d0 + p * 2);
        ((unsigned*)&su [t][0])[p] = *(const unsigned*)(u  + (size_t)(row0 + t) * DINNER + d0 + p * 2);
        ((unsigned*)&sz [t][0])[p] = *(const unsigned*)((const __bf16*)zy + (size_t)(row0 + t) * DINNER + d0 + p * 2);
    }
#pragma unroll
    for (int i = 0; i < 8; ++i) {
        int idx = i * 64 + lane, t = idx >> 3, q = idx & 7;
        *(floatx4*)&sBC[t][q * 4] = *(const floatx4*)&xdbl[(size_t)(row0 + t) * 96 + 64 + q * 4];
    }
    __syncthreads();

    float A[DSTATE], h[DSTATE];
    size_t ch = ((size_t)(b * DINNER + d) * CHUNKS + c);
#pragma unroll
    for (int s = 0; s < DSTATE; ++s) {
        A[s] = -__expf(Alog[d * DSTATE + s]);
        h[s] = (float)Hfix[ch * DSTATE + s];
    }
    float Dv = Dp[d];

    for (int t = 0; t < CLEN; ++t) {
        float dtv = (float)sdt[t][lane];
        float uv  = (float)su[t][lane];
        float du  = dtv * uv;
        float yv  = 0.f;
#pragma unroll
        for (int s = 0; s < DSTATE; ++s) {
            h[s] = __expf(dtv * A[s]) * h[s] + du * sBC[t][s];
            yv  += h[s] * sBC[t][DSTATE + s];
        }
        float zv = (float)sz[t][lane];
        float sg = zv / (1.f + __expf(-zv));
        zy[(size_t)(row0 + t) * DINNER + d] = (__bf16)((yv + uv * Dv) * sg);
    }
}

// ---------------------------------------------------------------------------
extern "C" void kernel_launch(void* const* d_in, const int* in_sizes, int n_in,
                              void* d_out, int out_size, void* d_ws, size_t ws_size,
                              hipStream_t stream) {
    const float* x      = (const float*)d_in[0];
    const float* ln_w   = (const float*)d_in[1];
    const float* ln_b   = (const float*)d_in[2];
    const float* W_in   = (const float*)d_in[3];
    const float* conv_w = (const float*)d_in[4];
    const float* conv_b = (const float*)d_in[5];
    const float* W_x    = (const float*)d_in[6];
    const float* W_dt   = (const float*)d_in[7];
    const float* b_dt   = (const float*)d_in[8];
    const float* A_log  = (const float*)d_in[9];
    const float* Dp     = (const float*)d_in[10];
    const float* W_out  = (const float*)d_in[11];
    float* out = (float*)d_out;

    // Workspace, 56 MiB peak:
    //   [ 0,  8M)  xn bf16 (dead after GEMM1) -> { xdbl fp32 [0,1.5M),
    //              Sdt fp32 [1.5M,2M), Hfix bf16 [2M,6M) }
    //   [ 8M,24M)  x_in bf16 (dead after conv) -> dt bf16
    //   [24M,40M)  z bf16; scan pass3 overwrites with y in place
    //   [40M,56M)  Winb bf16 8M (dead after GEMM1) -> u bf16 16M (conv..pass3)
    //              -> Woutb bf16 4M (after pass3)
    char* ws = (char*)d_ws;
    __bf16* xn_bf  = (__bf16*)(ws);
    float*  xdbl   = (float*) (ws);
    float*  Sdt    = (float*) (ws + 1536ull * 1024);
    __bf16* Hfix   = (__bf16*)(ws + (2ull  << 20));
    __bf16* xin_bf = (__bf16*)(ws + (8ull  << 20));
    __bf16* dt_bf  = (__bf16*)(ws + (8ull  << 20));
    __bf16* zy_bf  = (__bf16*)(ws + (24ull << 20));
    __bf16* Winb   = (__bf16*)(ws + (40ull << 20));
    __bf16* u_bf   = (__bf16*)(ws + (40ull << 20));
    __bf16* Woutb  = (__bf16*)(ws + (40ull << 20));

    ln_kernel<<<MROWS, 256, 0, stream>>>(x, ln_w, ln_b, xn_bf);

    w2bf<<<(2 * DINNER * DMODEL) / 1024, 256, 0, stream>>>(W_in, Winb, 2 * DINNER * DMODEL);

    gemm_as<1, 4><<<dim3(2 * DINNER / 128, MROWS / 128), 256, 0, stream>>>(
        xn_bf, Winb, MROWS, 2 * DINNER, DMODEL, xin_bf, zy_bf, nullptr, nullptr, DINNER);

    conv_kernel<<<MROWS * DINNER / 256, 256, 0, stream>>>(xin_bf, conv_w, conv_b, u_bf);

    // xdbl overlaps dead xn; zero it for split-K atomic accumulation
    hipMemsetAsync(xdbl, 0, (size_t)MROWS * 96 * sizeof(float), stream);

    wx_mfma<<<dim3(MROWS / BM, WX_KS), 256, 0, stream>>>(u_bf, W_x, xdbl);

    dt_mfma<<<dim3(DINNER / BN, MROWS / BM), 256, 0, stream>>>(xdbl, W_dt, b_dt, dt_bf);

    dim3 sgrid(CHUNKS, DINNER / 64, BATCH);
    scan_pass1<<<sgrid, 64, 0, stream>>>(dt_bf, u_bf, xdbl, A_log, Sdt, Hfix);
    scan_pass2<<<BATCH * DINNER * DSTATE / 256, 256, 0, stream>>>(A_log, Sdt, Hfix);
    scan_pass3<<<sgrid, 64, 0, stream>>>(dt_bf, u_bf, xdbl, A_log, Dp, Hfix, zy_bf);

    w2bf<<<(DMODEL * DINNER) / 1024, 256, 0, stream>>>(W_out, Woutb, DMODEL * DINNER);

    gemm_as<2, 2><<<dim3(DMODEL / 64, MROWS / 128), 256, 0, stream>>>(
        zy_bf, Woutb, MROWS, DMODEL, DINNER, nullptr, nullptr, out, x, 0);
}

// Round 10
// 426.706 us; speedup vs baseline: 6.9166x; 1.0484x over previous
//
#include <hip/hip_runtime.h>

// ---------------------------------------------------------------------------
// Mamba block. fp32 in/out. Internal: bf16 MFMA operands, fp32 accumulation
// and scan state.
// R10: scan_pass1/3 de-LDS'd. Per-lane streams (dt/u/z) are read directly
// from global (same coalesced 128B/wave transaction, no LDS round-trip);
// B/C are wave-uniform floatx4 broadcast loads (1 L1 transaction vs 32
// ds_read_b32/t). LDS=0 -> residency no longer 5 blocks/CU (was 32KB/block).
// ---------------------------------------------------------------------------
#define BATCH   2
#define SEQ     2048
#define DMODEL  1024
#define DINNER  2048
#define DSTATE  16
#define DTRANK  64
#define MROWS   (BATCH * SEQ)   // 4096
#define CLEN    64              // scan chunk length
#define CHUNKS  (SEQ / CLEN)    // 32

typedef float floatx4 __attribute__((ext_vector_type(4)));
typedef __bf16 bf16x8 __attribute__((ext_vector_type(8)));

__device__ __forceinline__ void async_cp16(void* lds, const void* g) {
    __builtin_amdgcn_global_load_lds((const __attribute__((address_space(1))) void*)g,
                                     (__attribute__((address_space(3))) void*)lds, 16, 0, 0);
}

// ---------------------------------------------------------------------------
// K0: fp32 -> bf16 weight conversion
// ---------------------------------------------------------------------------
__global__ __launch_bounds__(256) void w2bf(const float* __restrict__ w,
                                            __bf16* __restrict__ o, int n) {
    int i = (blockIdx.x * 256 + threadIdx.x) * 4;
    if (i < n) {
        floatx4 v = *(const floatx4*)&w[i];
        __bf16 r[4];
#pragma unroll
        for (int t = 0; t < 4; ++t) r[t] = (__bf16)v[t];
        *(unsigned long long*)&o[i] = *(unsigned long long*)r;
    }
}

// ---------------------------------------------------------------------------
// K1: LayerNorm.  One block per row of 1024.  fp32 in, bf16 out (GEMM A-op).
// ---------------------------------------------------------------------------
__global__ __launch_bounds__(256) void ln_kernel(const float* __restrict__ x,
                                                 const float* __restrict__ w,
                                                 const float* __restrict__ b,
                                                 __bf16* __restrict__ xn) {
    int row = blockIdx.x;
    const float* xr = x + (size_t)row * DMODEL;
    float v[4], s = 0.f, ss = 0.f;
#pragma unroll
    for (int i = 0; i < 4; ++i) {
        v[i] = xr[threadIdx.x + i * 256];
        s += v[i]; ss += v[i] * v[i];
    }
#pragma unroll
    for (int o = 32; o > 0; o >>= 1) { s += __shfl_xor(s, o); ss += __shfl_xor(ss, o); }
    __shared__ float ps[4], pss[4];
    int wv = threadIdx.x >> 6;
    if ((threadIdx.x & 63) == 0) { ps[wv] = s; pss[wv] = ss; }
    __syncthreads();
    s  = ps[0] + ps[1] + ps[2] + ps[3];
    ss = pss[0] + pss[1] + pss[2] + pss[3];
    float mu  = s * (1.f / DMODEL);
    float var = ss * (1.f / DMODEL) - mu * mu;
    float rs  = rsqrtf(var + 1e-5f);
#pragma unroll
    for (int i = 0; i < 4; ++i) {
        int c = threadIdx.x + i * 256;
        xn[(size_t)row * DMODEL + c] = (__bf16)((v[i] - mu) * rs * w[c] + b[c]);
    }
}

// ---------------------------------------------------------------------------
// K2: async-staged MFMA GEMM.  C[M,N] = A[M,K] * B[N,K]^T, A,B bf16.
// Tile 128 x (NW*32), BK=32, 4 waves (2x2), wave = 64m x (NW*16)n.
// EPI=1: split -> out0 bf16 (n<split) / out1 bf16 (n>=split)
// EPI=2: residual -> outf fp32 = acc + add[idx]
// ---------------------------------------------------------------------------
template <int EPI, int NW>
__global__ __launch_bounds__(256) void gemm_as(const __bf16* __restrict__ A,
                                               const __bf16* __restrict__ Bb,
                                               int M, int N, int K,
                                               __bf16* __restrict__ out0,
                                               __bf16* __restrict__ out1,
                                               float* __restrict__ outf,
                                               const float* __restrict__ add,
                                               int split) {
    constexpr int BNT = NW * 32;
    constexpr int NCH = 8 + BNT / 16;            // 1-KiB chunks per K-step
    __shared__ __align__(16) __bf16 sA[128 * 32];
    __shared__ __align__(16) __bf16 sB[BNT * 32];
    int tid  = threadIdx.x;
    int wave = tid >> 6, lane = tid & 63;
    int m0 = blockIdx.y * 128, n0 = blockIdx.x * BNT;
    int wm = (wave & 1) * 64, wn = (wave >> 1) * (NW * 16);
    int lr = lane & 15;
    int lq = lane >> 4;
    int r16 = lane >> 2;                         // row within a chunk
    int c8  = (lane & 3) * 8;                    // col (elements)

    floatx4 acc[4][NW] = {};

    for (int k0 = 0; k0 < K; k0 += 32) {
        for (int c = wave; c < NCH; c += 4) {
            if (c < 8) {
                const __bf16* g = A + (size_t)(m0 + c * 16 + r16) * K + k0 + c8;
                async_cp16(&sA[c * 512], g);
            } else {
                int cb = c - 8;
                const __bf16* g = Bb + (size_t)(n0 + cb * 16 + r16) * K + k0 + c8;
                async_cp16(&sB[cb * 512], g);
            }
        }
        __syncthreads();

        bf16x8 af[4], bfr[NW];
#pragma unroll
        for (int i = 0; i < 4; ++i)  af[i]  = *(const bf16x8*)&sA[(wm + i * 16 + lr) * 32 + lq * 8];
#pragma unroll
        for (int j = 0; j < NW; ++j) bfr[j] = *(const bf16x8*)&sB[(wn + j * 16 + lr) * 32 + lq * 8];
#pragma unroll
        for (int i = 0; i < 4; ++i)
#pragma unroll
            for (int j = 0; j < NW; ++j)
                acc[i][j] = __builtin_amdgcn_mfma_f32_16x16x32_bf16(af[i], bfr[j], acc[i][j], 0, 0, 0);
        __syncthreads();
    }

#pragma unroll
    for (int i = 0; i < 4; ++i)
#pragma unroll
        for (int j = 0; j < NW; ++j) {
            int gn = n0 + wn + j * 16 + lr;
#pragma unroll
            for (int r = 0; r < 4; ++r) {
                int gm = m0 + wm + i * 16 + lq * 4 + r;
                float v = acc[i][j][r];
                if (EPI == 1) {
                    if (gn < split) out0[(size_t)gm * split + gn] = (__bf16)v;
                    else            out1[(size_t)gm * split + (gn - split)] = (__bf16)v;
                } else {
                    size_t idx = (size_t)gm * N + gn;
                    outf[idx] = v + add[idx];
                }
            }
        }
}

// ---------------------------------------------------------------------------
// K3: depthwise causal conv (width 4) + bias + SiLU.
// ---------------------------------------------------------------------------
__global__ __launch_bounds__(256) void conv_kernel(const __bf16* __restrict__ xin,
                                                   const float* __restrict__ cw,
                                                   const float* __restrict__ cb,
                                                   __bf16* __restrict__ u) {
    int idx = blockIdx.x * 256 + threadIdx.x;        // over MROWS*DINNER
    int d  = idx & (DINNER - 1);
    int bl = idx >> 11;                              // b*SEQ + l
    int l  = bl & (SEQ - 1);
    float acc = cb[d];
#pragma unroll
    for (int j = 0; j < 4; ++j) {
        int ll = l - 3 + j;
        if (ll >= 0) acc += (float)xin[(size_t)(bl - 3 + j) * DINNER + d] * cw[d * 4 + j];
    }
    float sg = 1.f / (1.f + __expf(-acc));
    u[idx] = (__bf16)(acc * sg);
}

// ---------------------------------------------------------------------------
// K4 (MFMA, split-K): xdbl[4096,96] += u[4096,2048] @ Wx[96,2048]^T.
// ---------------------------------------------------------------------------
#define BM 128
#define BN 128
#define BK 32
#define LDK 48
#define WX_KS 16
#define WX_KSLICE (DINNER / WX_KS)   // 128

__global__ __launch_bounds__(256) void wx_mfma(const __bf16* __restrict__ A,
                                               const float* __restrict__ B,
                                               float* __restrict__ xdbl) {
    __shared__ __align__(16) __bf16 sA[BM][LDK];
    __shared__ __align__(16) __bf16 sB[96][LDK];
    int tid  = threadIdx.x;
    int wave = tid >> 6, lane = tid & 63;
    int m0 = blockIdx.x * BM;
    int k0base = blockIdx.y * WX_KSLICE;
    int wm = (wave & 1) * 64, wn = (wave >> 1) * 48;
    int lr = lane & 15;
    int lq = lane >> 4;

    floatx4 acc[4][3] = {};

    for (int k0 = k0base; k0 < k0base + WX_KSLICE; k0 += BK) {
#pragma unroll
        for (int c = tid; c < 512; c += 256) {
            int row = c >> 2, col = (c & 3) * 8;
            *(bf16x8*)&sA[row][col] = *(const bf16x8*)&A[(size_t)(m0 + row) * DINNER + k0 + col];
        }
        for (int c = tid; c < 384; c += 256) {
            int row = c >> 2, col = (c & 3) * 8;
            const float* src = B + (size_t)row * DINNER + k0 + col;
            floatx4 lo = *(const floatx4*)src;
            floatx4 hi = *(const floatx4*)(src + 4);
            bf16x8 v;
#pragma unroll
            for (int t = 0; t < 4; ++t) { v[t] = (__bf16)lo[t]; v[4 + t] = (__bf16)hi[t]; }
            *(bf16x8*)&sB[row][col] = v;
        }
        __syncthreads();

        bf16x8 af[4], bfr[3];
#pragma unroll
        for (int i = 0; i < 4; ++i) af[i]  = *(const bf16x8*)&sA[wm + i * 16 + lr][lq * 8];
#pragma unroll
        for (int j = 0; j < 3; ++j) bfr[j] = *(const bf16x8*)&sB[wn + j * 16 + lr][lq * 8];
#pragma unroll
        for (int i = 0; i < 4; ++i)
#pragma unroll
            for (int j = 0; j < 3; ++j)
                acc[i][j] = __builtin_amdgcn_mfma_f32_16x16x32_bf16(af[i], bfr[j], acc[i][j], 0, 0, 0);
        __syncthreads();
    }

#pragma unroll
    for (int i = 0; i < 4; ++i)
#pragma unroll
        for (int j = 0; j < 3; ++j) {
            int gn = wn + j * 16 + lr;
#pragma unroll
            for (int r = 0; r < 4; ++r) {
                int gm = m0 + wm + i * 16 + lq * 4 + r;
                unsafeAtomicAdd(&xdbl[(size_t)gm * 96 + gn], acc[i][j][r]);
            }
        }
}

// ---------------------------------------------------------------------------
// K5 (MFMA): dt[4096,2048] = softplus(xdbl[:,0:64] @ Wdt[2048,64]^T + b_dt)
// ---------------------------------------------------------------------------
__global__ __launch_bounds__(256) void dt_mfma(const float* __restrict__ Af,
                                               const float* __restrict__ B,
                                               const float* __restrict__ bdt,
                                               __bf16* __restrict__ dt) {
    __shared__ __align__(16) __bf16 sA[BM][LDK];
    __shared__ __align__(16) __bf16 sB[BN][LDK];
    int tid  = threadIdx.x;
    int wave = tid >> 6, lane = tid & 63;
    int m0 = blockIdx.y * BM, n0 = blockIdx.x * BN;
    int wm = (wave & 1) * 64, wn = (wave >> 1) * 64;
    int lr = lane & 15;
    int lq = lane >> 4;

    floatx4 acc[4][4] = {};

    for (int k0 = 0; k0 < DTRANK; k0 += BK) {
#pragma unroll
        for (int c = tid; c < 512; c += 256) {
            int row = c >> 2, col = (c & 3) * 8;
            const float* src = Af + (size_t)(m0 + row) * 96 + k0 + col;
            floatx4 lo = *(const floatx4*)src;
            floatx4 hi = *(const floatx4*)(src + 4);
            bf16x8 v;
#pragma unroll
            for (int t = 0; t < 4; ++t) { v[t] = (__bf16)lo[t]; v[4 + t] = (__bf16)hi[t]; }
            *(bf16x8*)&sA[row][col] = v;
        }
#pragma unroll
        for (int c = tid; c < 512; c += 256) {
            int row = c >> 2, col = (c & 3) * 8;
            const float* src = B + (size_t)(n0 + row) * DTRANK + k0 + col;
            floatx4 lo = *(const floatx4*)src;
            floatx4 hi = *(const floatx4*)(src + 4);
            bf16x8 v;
#pragma unroll
            for (int t = 0; t < 4; ++t) { v[t] = (__bf16)lo[t]; v[4 + t] = (__bf16)hi[t]; }
            *(bf16x8*)&sB[row][col] = v;
        }
        __syncthreads();

        bf16x8 af[4], bfr[4];
#pragma unroll
        for (int i = 0; i < 4; ++i) af[i]  = *(const bf16x8*)&sA[wm + i * 16 + lr][lq * 8];
#pragma unroll
        for (int j = 0; j < 4; ++j) bfr[j] = *(const bf16x8*)&sB[wn + j * 16 + lr][lq * 8];
#pragma unroll
        for (int i = 0; i < 4; ++i)
#pragma unroll
            for (int j = 0; j < 4; ++j)
                acc[i][j] = __builtin_amdgcn_mfma_f32_16x16x32_bf16(af[i], bfr[j], acc[i][j], 0, 0, 0);
        __syncthreads();
    }

#pragma unroll
    for (int i = 0; i < 4; ++i)
#pragma unroll
        for (int j = 0; j < 4; ++j) {
            int gn = n0 + wn + j * 16 + lr;
            float bv = bdt[gn];
#pragma unroll
            for (int r = 0; r < 4; ++r) {
                int gm = m0 + wm + i * 16 + lq * 4 + r;
                float a = acc[i][j][r] + bv;
                float sp = (a > 20.f) ? a : log1pf(__expf(a));
                dt[(size_t)gm * DINNER + gn] = (__bf16)sp;
            }
        }
}

// ---------------------------------------------------------------------------
// K6 (3-pass chunked scan), LDS-free.
// pass1: per-chunk local scan (h0=0) -> Sdt (sum dt), Hfix (local end state)
// ---------------------------------------------------------------------------
__global__ __launch_bounds__(64) void scan_pass1(const __bf16* __restrict__ dt,
                                                 const __bf16* __restrict__ u,
                                                 const float* __restrict__ xdbl,
                                                 const float* __restrict__ Alog,
                                                 float* __restrict__ Sdt,
                                                 __bf16* __restrict__ Hfix) {
    int c = blockIdx.x, dblk = blockIdx.y, b = blockIdx.z;
    int lane = threadIdx.x;
    int d = dblk * 64 + lane;
    int row0 = b * SEQ + c * CLEN;

    const __bf16* dtp = dt + (size_t)row0 * DINNER + d;
    const __bf16* up  = u  + (size_t)row0 * DINNER + d;
    const float*  bcp = xdbl + (size_t)row0 * 96 + 64;

    float A[DSTATE], h[DSTATE];
#pragma unroll
    for (int s = 0; s < DSTATE; ++s) { A[s] = -__expf(Alog[d * DSTATE + s]); h[s] = 0.f; }

    float S = 0.f;
    for (int t = 0; t < CLEN; ++t) {
        float dtv = (float)dtp[(size_t)t * DINNER];
        float uv  = (float)up [(size_t)t * DINNER];
        floatx4 B0 = *(const floatx4*)(bcp + t * 96);
        floatx4 B1 = *(const floatx4*)(bcp + t * 96 + 4);
        floatx4 B2 = *(const floatx4*)(bcp + t * 96 + 8);
        floatx4 B3 = *(const floatx4*)(bcp + t * 96 + 12);
        S += dtv;
        float du = dtv * uv;
#pragma unroll
        for (int s = 0; s < 4; ++s) {
            h[s]      = __expf(dtv * A[s])      * h[s]      + du * B0[s];
            h[4 + s]  = __expf(dtv * A[4 + s])  * h[4 + s]  + du * B1[s];
            h[8 + s]  = __expf(dtv * A[8 + s])  * h[8 + s]  + du * B2[s];
            h[12 + s] = __expf(dtv * A[12 + s]) * h[12 + s] + du * B3[s];
        }
    }
    size_t ch = ((size_t)(b * DINNER + d) * CHUNKS + c);
    Sdt[ch] = S;
#pragma unroll
    for (int s = 0; s < DSTATE; ++s) Hfix[ch * DSTATE + s] = (__bf16)h[s];
}

// pass2: per-(b,d,s) chain over chunk summaries; Hfix -> h_init in place.
__global__ __launch_bounds__(256) void scan_pass2(const float* __restrict__ Alog,
                                                  const float* __restrict__ Sdt,
                                                  __bf16* __restrict__ Hfix) {
    int g = blockIdx.x * 256 + threadIdx.x;       // over BATCH*DINNER*DSTATE
    int s = g & (DSTATE - 1);
    int bd = g >> 4;
    int d = bd & (DINNER - 1);
    float A = -__expf(Alog[d * DSTATE + s]);
    size_t hbase = (size_t)bd * CHUNKS * DSTATE + s;
    size_t sbase = (size_t)bd * CHUNKS;
    float h = 0.f;
#pragma unroll 4
    for (int c = 0; c < CHUNKS; ++c) {
        float Hl = (float)Hfix[hbase + c * DSTATE];
        float P  = __expf(A * Sdt[sbase + c]);
        Hfix[hbase + c * DSTATE] = (__bf16)h;
        h = P * h + Hl;
    }
}

// pass3: recompute per-chunk scan from h_init; fused y=(y+u*D)*silu(z),
// written over z in place.  LDS-free (see R10 header).
__global__ __launch_bounds__(64) void scan_pass3(const __bf16* __restrict__ dt,
                                                 const __bf16* __restrict__ u,
                                                 const float* __restrict__ xdbl,
                                                 const float* __restrict__ Alog,
                                                 const float* __restrict__ Dp,
                                                 const __bf16* __restrict__ Hfix,
                                                 __bf16* zy) {
    int c = blockIdx.x, dblk = blockIdx.y, b = blockIdx.z;
    int lane = threadIdx.x;
    int d = dblk * 64 + lane;
    int row0 = b * SEQ + c * CLEN;

    const __bf16* dtp = dt + (size_t)row0 * DINNER + d;
    const __bf16* up  = u  + (size_t)row0 * DINNER + d;
    __bf16*       zyp = zy + (size_t)row0 * DINNER + d;
    const float*  bcp = xdbl + (size_t)row0 * 96 + 64;

    float A[DSTATE], h[DSTATE];
    size_t ch = ((size_t)(b * DINNER + d) * CHUNKS + c);
#pragma unroll
    for (int s = 0; s < DSTATE; ++s) {
        A[s] = -__expf(Alog[d * DSTATE + s]);
        h[s] = (float)Hfix[ch * DSTATE + s];
    }
    float Dv = Dp[d];

    for (int t = 0; t < CLEN; ++t) {
        float dtv = (float)dtp[(size_t)t * DINNER];
        float uv  = (float)up [(size_t)t * DINNER];
        float zv  = (float)zyp[(size_t)t * DINNER];
        floatx4 B0 = *(const floatx4*)(bcp + t * 96);
        floatx4 B1 = *(const floatx4*)(bcp + t * 96 + 4);
        floatx4 B2 = *(const floatx4*)(bcp + t * 96 + 8);
        floatx4 B3 = *(const floatx4*)(bcp + t * 96 + 12);
        floatx4 C0 = *(const floatx4*)(bcp + t * 96 + 16);
        floatx4 C1 = *(const floatx4*)(bcp + t * 96 + 20);
        floatx4 C2 = *(const floatx4*)(bcp + t * 96 + 24);
        floatx4 C3 = *(const floatx4*)(bcp + t * 96 + 28);
        float du = dtv * uv;
        float yv = 0.f;
#pragma unroll
        for (int s = 0; s < 4; ++s) {
            h[s]      = __expf(dtv * A[s])      * h[s]      + du * B0[s];
            h[4 + s]  = __expf(dtv * A[4 + s])  * h[4 + s]  + du * B1[s];
            h[8 + s]  = __expf(dtv * A[8 + s])  * h[8 + s]  + du * B2[s];
            h[12 + s] = __expf(dtv * A[12 + s]) * h[12 + s] + du * B3[s];
            yv += h[s] * C0[s] + h[4 + s] * C1[s] + h[8 + s] * C2[s] + h[12 + s] * C3[s];
        }
        float sg = zv / (1.f + __expf(-zv));
        zyp[(size_t)t * DINNER] = (__bf16)((yv + uv * Dv) * sg);
    }
}

// ---------------------------------------------------------------------------
extern "C" void kernel_launch(void* const* d_in, const int* in_sizes, int n_in,
                              void* d_out, int out_size, void* d_ws, size_t ws_size,
                              hipStream_t stream) {
    const float* x      = (const float*)d_in[0];
    const float* ln_w   = (const float*)d_in[1];
    const float* ln_b   = (const float*)d_in[2];
    const float* W_in   = (const float*)d_in[3];
    const float* conv_w = (const float*)d_in[4];
    const float* conv_b = (const float*)d_in[5];
    const float* W_x    = (const float*)d_in[6];
    const float* W_dt   = (const float*)d_in[7];
    const float* b_dt   = (const float*)d_in[8];
    const float* A_log  = (const float*)d_in[9];
    const float* Dp     = (const float*)d_in[10];
    const float* W_out  = (const float*)d_in[11];
    float* out = (float*)d_out;

    // Workspace, 56 MiB peak:
    //   [ 0,  8M)  xn bf16 (dead after GEMM1) -> { xdbl fp32 [0,1.5M),
    //              Sdt fp32 [1.5M,2M), Hfix bf16 [2M,6M) }
    //   [ 8M,24M)  x_in bf16 (dead after conv) -> dt bf16
    //   [24M,40M)  z bf16; scan pass3 overwrites with y in place
    //   [40M,56M)  Winb bf16 8M (dead after GEMM1) -> u bf16 16M (conv..pass3)
    //              -> Woutb bf16 4M (after pass3)
    char* ws = (char*)d_ws;
    __bf16* xn_bf  = (__bf16*)(ws);
    float*  xdbl   = (float*) (ws);
    float*  Sdt    = (float*) (ws + 1536ull * 1024);
    __bf16* Hfix   = (__bf16*)(ws + (2ull  << 20));
    __bf16* xin_bf = (__bf16*)(ws + (8ull  << 20));
    __bf16* dt_bf  = (__bf16*)(ws + (8ull  << 20));
    __bf16* zy_bf  = (__bf16*)(ws + (24ull << 20));
    __bf16* Winb   = (__bf16*)(ws + (40ull << 20));
    __bf16* u_bf   = (__bf16*)(ws + (40ull << 20));
    __bf16* Woutb  = (__bf16*)(ws + (40ull << 20));

    ln_kernel<<<MROWS, 256, 0, stream>>>(x, ln_w, ln_b, xn_bf);

    w2bf<<<(2 * DINNER * DMODEL) / 1024, 256, 0, stream>>>(W_in, Winb, 2 * DINNER * DMODEL);

    gemm_as<1, 4><<<dim3(2 * DINNER / 128, MROWS / 128), 256, 0, stream>>>(
        xn_bf, Winb, MROWS, 2 * DINNER, DMODEL, xin_bf, zy_bf, nullptr, nullptr, DINNER);

    conv_kernel<<<MROWS * DINNER / 256, 256, 0, stream>>>(xin_bf, conv_w, conv_b, u_bf);

    // xdbl overlaps dead xn; zero it for split-K atomic accumulation
    hipMemsetAsync(xdbl, 0, (size_t)MROWS * 96 * sizeof(float), stream);

    wx_mfma<<<dim3(MROWS / BM, WX_KS), 256, 0, stream>>>(u_bf, W_x, xdbl);

    dt_mfma<<<dim3(DINNER / BN, MROWS / BM), 256, 0, stream>>>(xdbl, W_dt, b_dt, dt_bf);

    dim3 sgrid(CHUNKS, DINNER / 64, BATCH);
    scan_pass1<<<sgrid, 64, 0, stream>>>(dt_bf, u_bf, xdbl, A_log, Sdt, Hfix);
    scan_pass2<<<BATCH * DINNER * DSTATE / 256, 256, 0, stream>>>(A_log, Sdt, Hfix);
    scan_pass3<<<sgrid, 64, 0, stream>>>(dt_bf, u_bf, xdbl, A_log, Dp, Hfix, zy_bf);

    w2bf<<<(DMODEL * DINNER) / 1024, 256, 0, stream>>>(W_out, Woutb, DMODEL * DINNER);

    gemm_as<2, 2><<<dim3(DMODEL / 64, MROWS / 128), 256, 0, stream>>>(
        zy_bf, Woutb, MROWS, DMODEL, DINNER, nullptr, nullptr, out, x, 0);
}

// Round 11
// 401.824 us; speedup vs baseline: 7.3449x; 1.0619x over previous
//
#include <hip/hip_runtime.h>

// ---------------------------------------------------------------------------
// Mamba block. fp32 in/out. Internal: bf16 MFMA operands, fp32 accumulation
// and scan state.
// R11: gemm_as K-loop restructured: BK=64 (halves barrier drains, 32 MFMA
// per barrier) + XOR-swizzled LDS layout (source-side swizzle, since
// global_load_lds pins lane->LDS dest). Read-side inverse applied in
// ds_read addressing. Kills the 4.2M bank-conflict cycles of R10.
// ---------------------------------------------------------------------------
#define BATCH   2
#define SEQ     2048
#define DMODEL  1024
#define DINNER  2048
#define DSTATE  16
#define DTRANK  64
#define MROWS   (BATCH * SEQ)   // 4096
#define CLEN    64              // scan chunk length
#define CHUNKS  (SEQ / CLEN)    // 32

typedef float floatx4 __attribute__((ext_vector_type(4)));
typedef __bf16 bf16x8 __attribute__((ext_vector_type(8)));

__device__ __forceinline__ void async_cp16(void* lds, const void* g) {
    __builtin_amdgcn_global_load_lds((const __attribute__((address_space(1))) void*)g,
                                     (__attribute__((address_space(3))) void*)lds, 16, 0, 0);
}

// ---------------------------------------------------------------------------
// K0: fp32 -> bf16 weight conversion
// ---------------------------------------------------------------------------
__global__ __launch_bounds__(256) void w2bf(const float* __restrict__ w,
                                            __bf16* __restrict__ o, int n) {
    int i = (blockIdx.x * 256 + threadIdx.x) * 4;
    if (i < n) {
        floatx4 v = *(const floatx4*)&w[i];
        __bf16 r[4];
#pragma unroll
        for (int t = 0; t < 4; ++t) r[t] = (__bf16)v[t];
        *(unsigned long long*)&o[i] = *(unsigned long long*)r;
    }
}

// ---------------------------------------------------------------------------
// K1: LayerNorm.  One block per row of 1024.  fp32 in, bf16 out (GEMM A-op).
// ---------------------------------------------------------------------------
__global__ __launch_bounds__(256) void ln_kernel(const float* __restrict__ x,
                                                 const float* __restrict__ w,
                                                 const float* __restrict__ b,
                                                 __bf16* __restrict__ xn) {
    int row = blockIdx.x;
    const float* xr = x + (size_t)row * DMODEL;
    float v[4], s = 0.f, ss = 0.f;
#pragma unroll
    for (int i = 0; i < 4; ++i) {
        v[i] = xr[threadIdx.x + i * 256];
        s += v[i]; ss += v[i] * v[i];
    }
#pragma unroll
    for (int o = 32; o > 0; o >>= 1) { s += __shfl_xor(s, o); ss += __shfl_xor(ss, o); }
    __shared__ float ps[4], pss[4];
    int wv = threadIdx.x >> 6;
    if ((threadIdx.x & 63) == 0) { ps[wv] = s; pss[wv] = ss; }
    __syncthreads();
    s  = ps[0] + ps[1] + ps[2] + ps[3];
    ss = pss[0] + pss[1] + pss[2] + pss[3];
    float mu  = s * (1.f / DMODEL);
    float var = ss * (1.f / DMODEL) - mu * mu;
    float rs  = rsqrtf(var + 1e-5f);
#pragma unroll
    for (int i = 0; i < 4; ++i) {
        int c = threadIdx.x + i * 256;
        xn[(size_t)row * DMODEL + c] = (__bf16)((v[i] - mu) * rs * w[c] + b[c]);
    }
}

// ---------------------------------------------------------------------------
// K2: async-staged MFMA GEMM.  C[M,N] = A[M,K] * B[N,K]^T, A,B bf16.
// Tile 128 x (NW*32), BK=64, 4 waves (2x2), wave = 64m x (NW*16)n.
// Chunk = 1 KiB = 8 rows x 128 B.  Source-side XOR swizzle: lane l of a
// chunk loads logical 16B-group (l&7)^(l>>3) of row c*8+(l>>3); physical
// LDS group pg holds logical group pg^(row&7).  ds_read uses the inverse:
// group (s*4+lq)^(lr&7) -> 8 lanes cover all 32 banks, 2-way alias (free).
// EPI=1: split -> out0 bf16 (n<split) / out1 bf16 (n>=split)
// EPI=2: residual -> outf fp32 = acc + add[idx]
// ---------------------------------------------------------------------------
template <int EPI, int NW>
__global__ __launch_bounds__(256) void gemm_as(const __bf16* __restrict__ A,
                                               const __bf16* __restrict__ Bb,
                                               int M, int N, int K,
                                               __bf16* __restrict__ out0,
                                               __bf16* __restrict__ out1,
                                               float* __restrict__ outf,
                                               const float* __restrict__ add,
                                               int split) {
    constexpr int BNT = NW * 32;
    constexpr int ACH = 16;                      // A chunks per K-step (128r x 128B)
    constexpr int NCH = ACH + BNT / 8;           // + B chunks
    __shared__ __align__(16) __bf16 sA[128 * 64];
    __shared__ __align__(16) __bf16 sB[BNT * 64];
    int tid  = threadIdx.x;
    int wave = tid >> 6, lane = tid & 63;
    int m0 = blockIdx.y * 128, n0 = blockIdx.x * BNT;
    int wm = (wave & 1) * 64, wn = (wave >> 1) * (NW * 16);
    int lr = lane & 15;
    int lq = lane >> 4;
    int srow = lane >> 3;                        // row within a chunk (0..7)
    int sg   = ((lane & 7) ^ srow) * 8;          // swizzled source elem group

    floatx4 acc[4][NW] = {};

    for (int k0 = 0; k0 < K; k0 += 64) {
        for (int c = wave; c < NCH; c += 4) {
            if (c < ACH) {
                const __bf16* g = A + (size_t)(m0 + c * 8 + srow) * K + k0 + sg;
                async_cp16(&sA[c * 512], g);
            } else {
                int cb = c - ACH;
                const __bf16* g = Bb + (size_t)(n0 + cb * 8 + srow) * K + k0 + sg;
                async_cp16(&sB[cb * 512], g);
            }
        }
        __syncthreads();

#pragma unroll
        for (int s = 0; s < 2; ++s) {
            bf16x8 af[4], bfr[NW];
#pragma unroll
            for (int i = 0; i < 4; ++i) {
                int row = wm + i * 16 + lr;
                af[i] = *(const bf16x8*)&sA[row * 64 + (((s * 4 + lq) ^ (lr & 7)) * 8)];
            }
#pragma unroll
            for (int j = 0; j < NW; ++j) {
                int row = wn + j * 16 + lr;
                bfr[j] = *(const bf16x8*)&sB[row * 64 + (((s * 4 + lq) ^ (lr & 7)) * 8)];
            }
#pragma unroll
            for (int i = 0; i < 4; ++i)
#pragma unroll
                for (int j = 0; j < NW; ++j)
                    acc[i][j] = __builtin_amdgcn_mfma_f32_16x16x32_bf16(af[i], bfr[j], acc[i][j], 0, 0, 0);
        }
        __syncthreads();
    }

#pragma unroll
    for (int i = 0; i < 4; ++i)
#pragma unroll
        for (int j = 0; j < NW; ++j) {
            int gn = n0 + wn + j * 16 + lr;
#pragma unroll
            for (int r = 0; r < 4; ++r) {
                int gm = m0 + wm + i * 16 + lq * 4 + r;
                float v = acc[i][j][r];
                if (EPI == 1) {
                    if (gn < split) out0[(size_t)gm * split + gn] = (__bf16)v;
                    else            out1[(size_t)gm * split + (gn - split)] = (__bf16)v;
                } else {
                    size_t idx = (size_t)gm * N + gn;
                    outf[idx] = v + add[idx];
                }
            }
        }
}

// ---------------------------------------------------------------------------
// K3: depthwise causal conv (width 4) + bias + SiLU.
// ---------------------------------------------------------------------------
__global__ __launch_bounds__(256) void conv_kernel(const __bf16* __restrict__ xin,
                                                   const float* __restrict__ cw,
                                                   const float* __restrict__ cb,
                                                   __bf16* __restrict__ u) {
    int idx = blockIdx.x * 256 + threadIdx.x;        // over MROWS*DINNER
    int d  = idx & (DINNER - 1);
    int bl = idx >> 11;                              // b*SEQ + l
    int l  = bl & (SEQ - 1);
    float acc = cb[d];
#pragma unroll
    for (int j = 0; j < 4; ++j) {
        int ll = l - 3 + j;
        if (ll >= 0) acc += (float)xin[(size_t)(bl - 3 + j) * DINNER + d] * cw[d * 4 + j];
    }
    float sg = 1.f / (1.f + __expf(-acc));
    u[idx] = (__bf16)(acc * sg);
}

// ---------------------------------------------------------------------------
// K4 (MFMA, split-K): xdbl[4096,96] += u[4096,2048] @ Wx[96,2048]^T.
// ---------------------------------------------------------------------------
#define BM 128
#define BN 128
#define BK 32
#define LDK 48
#define WX_KS 16
#define WX_KSLICE (DINNER / WX_KS)   // 128

__global__ __launch_bounds__(256) void wx_mfma(const __bf16* __restrict__ A,
                                               const float* __restrict__ B,
                                               float* __restrict__ xdbl) {
    __shared__ __align__(16) __bf16 sA[BM][LDK];
    __shared__ __align__(16) __bf16 sB[96][LDK];
    int tid  = threadIdx.x;
    int wave = tid >> 6, lane = tid & 63;
    int m0 = blockIdx.x * BM;
    int k0base = blockIdx.y * WX_KSLICE;
    int wm = (wave & 1) * 64, wn = (wave >> 1) * 48;
    int lr = lane & 15;
    int lq = lane >> 4;

    floatx4 acc[4][3] = {};

    for (int k0 = k0base; k0 < k0base + WX_KSLICE; k0 += BK) {
#pragma unroll
        for (int c = tid; c < 512; c += 256) {
            int row = c >> 2, col = (c & 3) * 8;
            *(bf16x8*)&sA[row][col] = *(const bf16x8*)&A[(size_t)(m0 + row) * DINNER + k0 + col];
        }
        for (int c = tid; c < 384; c += 256) {
            int row = c >> 2, col = (c & 3) * 8;
            const float* src = B + (size_t)row * DINNER + k0 + col;
            floatx4 lo = *(const floatx4*)src;
            floatx4 hi = *(const floatx4*)(src + 4);
            bf16x8 v;
#pragma unroll
            for (int t = 0; t < 4; ++t) { v[t] = (__bf16)lo[t]; v[4 + t] = (__bf16)hi[t]; }
            *(bf16x8*)&sB[row][col] = v;
        }
        __syncthreads();

        bf16x8 af[4], bfr[3];
#pragma unroll
        for (int i = 0; i < 4; ++i) af[i]  = *(const bf16x8*)&sA[wm + i * 16 + lr][lq * 8];
#pragma unroll
        for (int j = 0; j < 3; ++j) bfr[j] = *(const bf16x8*)&sB[wn + j * 16 + lr][lq * 8];
#pragma unroll
        for (int i = 0; i < 4; ++i)
#pragma unroll
            for (int j = 0; j < 3; ++j)
                acc[i][j] = __builtin_amdgcn_mfma_f32_16x16x32_bf16(af[i], bfr[j], acc[i][j], 0, 0, 0);
        __syncthreads();
    }

#pragma unroll
    for (int i = 0; i < 4; ++i)
#pragma unroll
        for (int j = 0; j < 3; ++j) {
            int gn = wn + j * 16 + lr;
#pragma unroll
            for (int r = 0; r < 4; ++r) {
                int gm = m0 + wm + i * 16 + lq * 4 + r;
                unsafeAtomicAdd(&xdbl[(size_t)gm * 96 + gn], acc[i][j][r]);
            }
        }
}

// ---------------------------------------------------------------------------
// K5 (MFMA): dt[4096,2048] = softplus(xdbl[:,0:64] @ Wdt[2048,64]^T + b_dt)
// ---------------------------------------------------------------------------
__global__ __launch_bounds__(256) void dt_mfma(const float* __restrict__ Af,
                                               const float* __restrict__ B,
                                               const float* __restrict__ bdt,
                                               __bf16* __restrict__ dt) {
    __shared__ __align__(16) __bf16 sA[BM][LDK];
    __shared__ __align__(16) __bf16 sB[BN][LDK];
    int tid  = threadIdx.x;
    int wave = tid >> 6, lane = tid & 63;
    int m0 = blockIdx.y * BM, n0 = blockIdx.x * BN;
    int wm = (wave & 1) * 64, wn = (wave >> 1) * 64;
    int lr = lane & 15;
    int lq = lane >> 4;

    floatx4 acc[4][4] = {};

    for (int k0 = 0; k0 < DTRANK; k0 += BK) {
#pragma unroll
        for (int c = tid; c < 512; c += 256) {
            int row = c >> 2, col = (c & 3) * 8;
            const float* src = Af + (size_t)(m0 + row) * 96 + k0 + col;
            floatx4 lo = *(const floatx4*)src;
            floatx4 hi = *(const floatx4*)(src + 4);
            bf16x8 v;
#pragma unroll
            for (int t = 0; t < 4; ++t) { v[t] = (__bf16)lo[t]; v[4 + t] = (__bf16)hi[t]; }
            *(bf16x8*)&sA[row][col] = v;
        }
#pragma unroll
        for (int c = tid; c < 512; c += 256) {
            int row = c >> 2, col = (c & 3) * 8;
            const float* src = B + (size_t)(n0 + row) * DTRANK + k0 + col;
            floatx4 lo = *(const floatx4*)src;
            floatx4 hi = *(const floatx4*)(src + 4);
            bf16x8 v;
#pragma unroll
            for (int t = 0; t < 4; ++t) { v[t] = (__bf16)lo[t]; v[4 + t] = (__bf16)hi[t]; }
            *(bf16x8*)&sB[row][col] = v;
        }
        __syncthreads();

        bf16x8 af[4], bfr[4];
#pragma unroll
        for (int i = 0; i < 4; ++i) af[i]  = *(const bf16x8*)&sA[wm + i * 16 + lr][lq * 8];
#pragma unroll
        for (int j = 0; j < 4; ++j) bfr[j] = *(const bf16x8*)&sB[wn + j * 16 + lr][lq * 8];
#pragma unroll
        for (int i = 0; i < 4; ++i)
#pragma unroll
            for (int j = 0; j < 4; ++j)
                acc[i][j] = __builtin_amdgcn_mfma_f32_16x16x32_bf16(af[i], bfr[j], acc[i][j], 0, 0, 0);
        __syncthreads();
    }

#pragma unroll
    for (int i = 0; i < 4; ++i)
#pragma unroll
        for (int j = 0; j < 4; ++j) {
            int gn = n0 + wn + j * 16 + lr;
            float bv = bdt[gn];
#pragma unroll
            for (int r = 0; r < 4; ++r) {
                int gm = m0 + wm + i * 16 + lq * 4 + r;
                float a = acc[i][j][r] + bv;
                float sp = (a > 20.f) ? a : log1pf(__expf(a));
                dt[(size_t)gm * DINNER + gn] = (__bf16)sp;
            }
        }
}

// ---------------------------------------------------------------------------
// K6 (3-pass chunked scan), LDS-free.
// ---------------------------------------------------------------------------
__global__ __launch_bounds__(64) void scan_pass1(const __bf16* __restrict__ dt,
                                                 const __bf16* __restrict__ u,
                                                 const float* __restrict__ xdbl,
                                                 const float* __restrict__ Alog,
                                                 float* __restrict__ Sdt,
                                                 __bf16* __restrict__ Hfix) {
    int c = blockIdx.x, dblk = blockIdx.y, b = blockIdx.z;
    int lane = threadIdx.x;
    int d = dblk * 64 + lane;
    int row0 = b * SEQ + c * CLEN;

    const __bf16* dtp = dt + (size_t)row0 * DINNER + d;
    const __bf16* up  = u  + (size_t)row0 * DINNER + d;
    const float*  bcp = xdbl + (size_t)row0 * 96 + 64;

    float A[DSTATE], h[DSTATE];
#pragma unroll
    for (int s = 0; s < DSTATE; ++s) { A[s] = -__expf(Alog[d * DSTATE + s]); h[s] = 0.f; }

    float S = 0.f;
    for (int t = 0; t < CLEN; ++t) {
        float dtv = (float)dtp[(size_t)t * DINNER];
        float uv  = (float)up [(size_t)t * DINNER];
        floatx4 B0 = *(const floatx4*)(bcp + t * 96);
        floatx4 B1 = *(const floatx4*)(bcp + t * 96 + 4);
        floatx4 B2 = *(const floatx4*)(bcp + t * 96 + 8);
        floatx4 B3 = *(const floatx4*)(bcp + t * 96 + 12);
        S += dtv;
        float du = dtv * uv;
#pragma unroll
        for (int s = 0; s < 4; ++s) {
            h[s]      = __expf(dtv * A[s])      * h[s]      + du * B0[s];
            h[4 + s]  = __expf(dtv * A[4 + s])  * h[4 + s]  + du * B1[s];
            h[8 + s]  = __expf(dtv * A[8 + s])  * h[8 + s]  + du * B2[s];
            h[12 + s] = __expf(dtv * A[12 + s]) * h[12 + s] + du * B3[s];
        }
    }
    size_t ch = ((size_t)(b * DINNER + d) * CHUNKS + c);
    Sdt[ch] = S;
#pragma unroll
    for (int s = 0; s < DSTATE; ++s) Hfix[ch * DSTATE + s] = (__bf16)h[s];
}

__global__ __launch_bounds__(256) void scan_pass2(const float* __restrict__ Alog,
                                                  const float* __restrict__ Sdt,
                                                  __bf16* __restrict__ Hfix) {
    int g = blockIdx.x * 256 + threadIdx.x;       // over BATCH*DINNER*DSTATE
    int s = g & (DSTATE - 1);
    int bd = g >> 4;
    int d = bd & (DINNER - 1);
    float A = -__expf(Alog[d * DSTATE + s]);
    size_t hbase = (size_t)bd * CHUNKS * DSTATE + s;
    size_t sbase = (size_t)bd * CHUNKS;
    float h = 0.f;
#pragma unroll 4
    for (int c = 0; c < CHUNKS; ++c) {
        float Hl = (float)Hfix[hbase + c * DSTATE];
        float P  = __expf(A * Sdt[sbase + c]);
        Hfix[hbase + c * DSTATE] = (__bf16)h;
        h = P * h + Hl;
    }
}

__global__ __launch_bounds__(64) void scan_pass3(const __bf16* __restrict__ dt,
                                                 const __bf16* __restrict__ u,
                                                 const float* __restrict__ xdbl,
                                                 const float* __restrict__ Alog,
                                                 const float* __restrict__ Dp,
                                                 const __bf16* __restrict__ Hfix,
                                                 __bf16* zy) {
    int c = blockIdx.x, dblk = blockIdx.y, b = blockIdx.z;
    int lane = threadIdx.x;
    int d = dblk * 64 + lane;
    int row0 = b * SEQ + c * CLEN;

    const __bf16* dtp = dt + (size_t)row0 * DINNER + d;
    const __bf16* up  = u  + (size_t)row0 * DINNER + d;
    __bf16*       zyp = zy + (size_t)row0 * DINNER + d;
    const float*  bcp = xdbl + (size_t)row0 * 96 + 64;

    float A[DSTATE], h[DSTATE];
    size_t ch = ((size_t)(b * DINNER + d) * CHUNKS + c);
#pragma unroll
    for (int s = 0; s < DSTATE; ++s) {
        A[s] = -__expf(Alog[d * DSTATE + s]);
        h[s] = (float)Hfix[ch * DSTATE + s];
    }
    float Dv = Dp[d];

    for (int t = 0; t < CLEN; ++t) {
        float dtv = (float)dtp[(size_t)t * DINNER];
        float uv  = (float)up [(size_t)t * DINNER];
        float zv  = (float)zyp[(size_t)t * DINNER];
        floatx4 B0 = *(const floatx4*)(bcp + t * 96);
        floatx4 B1 = *(const floatx4*)(bcp + t * 96 + 4);
        floatx4 B2 = *(const floatx4*)(bcp + t * 96 + 8);
        floatx4 B3 = *(const floatx4*)(bcp + t * 96 + 12);
        floatx4 C0 = *(const floatx4*)(bcp + t * 96 + 16);
        floatx4 C1 = *(const floatx4*)(bcp + t * 96 + 20);
        floatx4 C2 = *(const floatx4*)(bcp + t * 96 + 24);
        floatx4 C3 = *(const floatx4*)(bcp + t * 96 + 28);
        float du = dtv * uv;
        float yv = 0.f;
#pragma unroll
        for (int s = 0; s < 4; ++s) {
            h[s]      = __expf(dtv * A[s])      * h[s]      + du * B0[s];
            h[4 + s]  = __expf(dtv * A[4 + s])  * h[4 + s]  + du * B1[s];
            h[8 + s]  = __expf(dtv * A[8 + s])  * h[8 + s]  + du * B2[s];
            h[12 + s] = __expf(dtv * A[12 + s]) * h[12 + s] + du * B3[s];
            yv += h[s] * C0[s] + h[4 + s] * C1[s] + h[8 + s] * C2[s] + h[12 + s] * C3[s];
        }
        float sg = zv / (1.f + __expf(-zv));
        zyp[(size_t)t * DINNER] = (__bf16)((yv + uv * Dv) * sg);
    }
}

// ---------------------------------------------------------------------------
extern "C" void kernel_launch(void* const* d_in, const int* in_sizes, int n_in,
                              void* d_out, int out_size, void* d_ws, size_t ws_size,
                              hipStream_t stream) {
    const float* x      = (const float*)d_in[0];
    const float* ln_w   = (const float*)d_in[1];
    const float* ln_b   = (const float*)d_in[2];
    const float* W_in   = (const float*)d_in[3];
    const float* conv_w = (const float*)d_in[4];
    const float* conv_b = (const float*)d_in[5];
    const float* W_x    = (const float*)d_in[6];
    const float* W_dt   = (const float*)d_in[7];
    const float* b_dt   = (const float*)d_in[8];
    const float* A_log  = (const float*)d_in[9];
    const float* Dp     = (const float*)d_in[10];
    const float* W_out  = (const float*)d_in[11];
    float* out = (float*)d_out;

    // Workspace, 56 MiB peak:
    //   [ 0,  8M)  xn bf16 (dead after GEMM1) -> { xdbl fp32 [0,1.5M),
    //              Sdt fp32 [1.5M,2M), Hfix bf16 [2M,6M) }
    //   [ 8M,24M)  x_in bf16 (dead after conv) -> dt bf16
    //   [24M,40M)  z bf16; scan pass3 overwrites with y in place
    //   [40M,56M)  Winb bf16 8M (dead after GEMM1) -> u bf16 16M (conv..pass3)
    //              -> Woutb bf16 4M (after pass3)
    char* ws = (char*)d_ws;
    __bf16* xn_bf  = (__bf16*)(ws);
    float*  xdbl   = (float*) (ws);
    float*  Sdt    = (float*) (ws + 1536ull * 1024);
    __bf16* Hfix   = (__bf16*)(ws + (2ull  << 20));
    __bf16* xin_bf = (__bf16*)(ws + (8ull  << 20));
    __bf16* dt_bf  = (__bf16*)(ws + (8ull  << 20));
    __bf16* zy_bf  = (__bf16*)(ws + (24ull << 20));
    __bf16* Winb   = (__bf16*)(ws + (40ull << 20));
    __bf16* u_bf   = (__bf16*)(ws + (40ull << 20));
    __bf16* Woutb  = (__bf16*)(ws + (40ull << 20));

    ln_kernel<<<MROWS, 256, 0, stream>>>(x, ln_w, ln_b, xn_bf);

    w2bf<<<(2 * DINNER * DMODEL) / 1024, 256, 0, stream>>>(W_in, Winb, 2 * DINNER * DMODEL);

    gemm_as<1, 4><<<dim3(2 * DINNER / 128, MROWS / 128), 256, 0, stream>>>(
        xn_bf, Winb, MROWS, 2 * DINNER, DMODEL, xin_bf, zy_bf, nullptr, nullptr, DINNER);

    conv_kernel<<<MROWS * DINNER / 256, 256, 0, stream>>>(xin_bf, conv_w, conv_b, u_bf);

    // xdbl overlaps dead xn; zero it for split-K atomic accumulation
    hipMemsetAsync(xdbl, 0, (size_t)MROWS * 96 * sizeof(float), stream);

    wx_mfma<<<dim3(MROWS / BM, WX_KS), 256, 0, stream>>>(u_bf, W_x, xdbl);

    dt_mfma<<<dim3(DINNER / BN, MROWS / BM), 256, 0, stream>>>(xdbl, W_dt, b_dt, dt_bf);

    dim3 sgrid(CHUNKS, DINNER / 64, BATCH);
    scan_pass1<<<sgrid, 64, 0, stream>>>(dt_bf, u_bf, xdbl, A_log, Sdt, Hfix);
    scan_pass2<<<BATCH * DINNER * DSTATE / 256, 256, 0, stream>>>(A_log, Sdt, Hfix);
    scan_pass3<<<sgrid, 64, 0, stream>>>(dt_bf, u_bf, xdbl, A_log, Dp, Hfix, zy_bf);

    w2bf<<<(DMODEL * DINNER) / 1024, 256, 0, stream>>>(W_out, Woutb, DMODEL * DINNER);

    gemm_as<2, 2><<<dim3(DMODEL / 64, MROWS / 128), 256, 0, stream>>>(
        zy_bf, Woutb, MROWS, DMODEL, DINNER, nullptr, nullptr, out, x, 0);
}